// Round 11
// baseline (342.077 us; speedup 1.0000x reference)
//
#include <hip/hip_runtime.h>

typedef unsigned short u16;
typedef __attribute__((ext_vector_type(8))) __bf16 bf16x8;
typedef __attribute__((ext_vector_type(4))) float f32x4;
typedef __attribute__((ext_vector_type(4))) unsigned short u16x4;
typedef __attribute__((ext_vector_type(8))) unsigned short u16x8;

#define NF    39
#define NNUM  13
#define NCAT  26
#define VOC   100000
#define NPAIR 741
#define KHID  23712   /* 2*741*16 */
#define BATCH 4096
#define HD1   1024
#define HD2   512
#define HD3   256

__device__ __forceinline__ u16 f2bf(float f) {
  unsigned u = __builtin_bit_cast(unsigned, f);
  return (u16)((u + 0x7fffu + ((u >> 16) & 1u)) >> 16);   // RNE
}

__device__ __forceinline__ void gload16(const void* g, void* l) {
  __builtin_amdgcn_global_load_lds((const __attribute__((address_space(1))) void*)g,
                                   (__attribute__((address_space(3))) void*)l, 16, 0, 0);
}

// ---------------------------------------------------------------------------
// Front end, 2 rows per block (round-10 proven)
// ---------------------------------------------------------------------------
__global__ __launch_bounds__(256) void fuse_front(
    const int* __restrict__ cat, const float* __restrict__ num,
    const float* __restrict__ tables, const float* __restrict__ nemb,
    const float* __restrict__ Wse1, const float* __restrict__ Wse2,
    const float* __restrict__ Wbil, u16* __restrict__ hid)
{
  __shared__ float xs[2][NF][16];
  __shared__ float wb[NF][16][16];
  __shared__ float pr[2][NF][16];
  __shared__ float Zs[2][NF], Ts[2][NNUM], As[2][NF];
  __shared__ unsigned char pis[NPAIR], pjs[NPAIR];

  const int b0 = blockIdx.x * 2;
  const int tid = threadIdx.x;

  for (int i = tid; i < NF * 64; i += 256)
    ((f32x4*)wb)[i] = ((const f32x4*)Wbil)[i];

  for (int t = tid; t < 2 * NNUM * 16; t += 256) {
    int r = t / (NNUM * 16), t2 = t % (NNUM * 16);
    int f = t2 >> 4, e = t2 & 15;
    xs[r][f][e] = num[(b0 + r) * NNUM + f] * nemb[t2];
  }
  for (int t = tid; t < 2 * NCAT * 16; t += 256) {
    int r = t / (NCAT * 16), t2 = t % (NCAT * 16);
    int c = t2 >> 4, e = t2 & 15;
    int cv = cat[(b0 + r) * NCAT + c];
    xs[r][NNUM + c][e] = tables[((size_t)c * VOC + cv) * 16 + e];
  }
  for (int p = tid; p < NPAIR; p += 256) {
    int i = 0, rs = 0;
    while (p >= rs + (NF - 1 - i)) { rs += NF - 1 - i; ++i; }
    pis[p] = (unsigned char)i;
    pjs[p] = (unsigned char)(i + 1 + (p - rs));
  }
  __syncthreads();

  if (tid < 2 * NF) {
    int r = tid / NF, f = tid % NF;
    float s = 0.f;
    #pragma unroll
    for (int e = 0; e < 16; ++e) s += xs[r][f][e];
    Zs[r][f] = s * (1.f / 16.f);
  }
  __syncthreads();
  if (tid < 2 * NNUM) {
    int r = tid / NNUM, o = tid % NNUM;
    float s = 0.f;
    for (int f = 0; f < NF; ++f) s += Zs[r][f] * Wse1[f * NNUM + o];
    Ts[r][o] = fmaxf(s, 0.f);
  }
  __syncthreads();
  if (tid < 2 * NF) {
    int r = tid / NF, f = tid % NF;
    float s = 0.f;
    for (int q = 0; q < NNUM; ++q) s += Ts[r][q] * Wse2[q * NF + f];
    As[r][f] = fmaxf(s, 0.f);
  }
  for (int t = tid; t < 2 * NF * 16; t += 256) {
    int r = t / (NF * 16), t2 = t % (NF * 16);
    int f = t2 >> 4, d = t2 & 15;
    float s = 0.f;
    #pragma unroll
    for (int e = 0; e < 16; ++e) s += xs[r][f][e] * wb[f][e][d];
    pr[r][f][d] = s;
  }
  __syncthreads();

  for (int idx = tid; idx < 2 * NPAIR * 2; idx += 256) {
    const int r = idx / (NPAIR * 2), idx2 = idx % (NPAIR * 2);
    const int p = idx2 >> 1, e0 = (idx2 & 1) * 8;
    const int i = pis[p], j = pjs[p];
    const float aa = As[r][i] * As[r][j];
    u16* hr = hid + (size_t)(b0 + r) * KHID;
    u16x8 vb, vs;
    #pragma unroll
    for (int e = 0; e < 8; ++e) {
      float bv = pr[r][i][e0 + e] * xs[r][j][e0 + e];
      vb[e] = f2bf(bv);
      vs[e] = f2bf(aa * bv);
    }
    *reinterpret_cast<u16x8*>(hr + NPAIR * 16 + p * 16 + e0) = vb;
    *reinterpret_cast<u16x8*>(hr + p * 16 + e0) = vs;
  }
}

// ---------------------------------------------------------------------------
// Merged transpose+cast (round-9 proven)
// ---------------------------------------------------------------------------
__global__ __launch_bounds__(256) void transpose_all(
    const float* __restrict__ Wd1, const float* __restrict__ Wd2,
    const float* __restrict__ Wd3, u16* __restrict__ W1t,
    u16* __restrict__ W2t, u16* __restrict__ W3t)
{
  __shared__ float t[32][33];
  const int bid = blockIdx.x;
  const float* in; u16* out; int K, N, kb, nb;
  if (bid < 741 * 32)        { in = Wd1; out = W1t; K = KHID; N = HD1; kb = bid % 741; nb = bid / 741; }
  else if (bid < 741 * 32 + 512) { int r = bid - 741 * 32; in = Wd2; out = W2t; K = HD1; N = HD2; kb = r % 32; nb = r / 32; }
  else                       { int r = bid - 741 * 32 - 512; in = Wd3; out = W3t; K = HD2; N = HD3; kb = r % 16; nb = r / 16; }

  const int k0 = kb * 32, n0 = nb * 32;
  const int c = threadIdx.x & 31, r = threadIdx.x >> 5;
  #pragma unroll
  for (int it = 0; it < 4; ++it)
    t[r + it * 8][c] = in[(size_t)(k0 + r + it * 8) * N + n0 + c];
  __syncthreads();
  const int n = threadIdx.x >> 3, kq = (threadIdx.x & 7) * 4;
  u16x4 v;
  #pragma unroll
  for (int q = 0; q < 4; ++q) v[q] = f2bf(t[kq + q][n]);
  *reinterpret_cast<u16x4*>(out + (size_t)(n0 + n) * K + k0 + kq) = v;
}

// ---------------------------------------------------------------------------
// 256x256 8-wave GEMM, cross-phase register prefetch + counted lgkm/vmcnt.
// Phase p: {barrier; stage; issue p+1's ds_reads (alt regs); lgkmcnt(4|8)
// (forces only p's fragments; p+1's drain under MFMA); 16 MFMA}.
// 1 barrier/phase. vmcnt(6) at P2-end (forces next-kk0 granules before P3's
// cross-tile prefetch) and P3-end (forces next-kk1) — ledger-verified.
// Stage W-A-R: each staged slot's last reads covered by prev phase's lgkm,
// which precedes its MFMA, which precedes this phase-top barrier.
// MFMA operand order identical to round 10 -> absmax canary 2.980232e-08.
// ---------------------------------------------------------------------------
__global__ __launch_bounds__(512, 2) void gemm8p_bf16(
    const u16* __restrict__ A, const u16* __restrict__ Bt,
    float* __restrict__ Cp, int M, int N, int K, int totku, int kpb)
{
  __shared__ __align__(16) u16 lds[65536];   // A slots @0, B slots @32768

  const int tid = threadIdx.x;
  const int wid = tid >> 6, lane = tid & 63;

  const int d = blockIdx.x;
  const int x = d & 7, jj = d >> 3;
  const int mb = ((x & 3) << 2) | (jj & 3);
  const int nb = (jj >> 2) & 3;
  const int sb = ((x >> 2) << 1) | (jj >> 4);

  const int ks0 = sb * kpb;
  const int kunits = (totku - ks0 < kpb) ? (totku - ks0) : kpb;
  const int ftiles = kunits >> 1;

  const int wm = wid >> 2, wn = wid & 3;
  const int lrow = lane & 15, c0 = lane >> 4;

  const int rr = tid >> 2, cc = tid & 3, csrc = cc ^ ((rr >> 1) & 3);
  const u16* pAg = A  + (size_t)((size_t)mb * 256 + rr) * K + (size_t)ks0 * 32 + csrc * 8;
  const u16* pBg = Bt + (size_t)((size_t)nb * 256 + rr) * K + (size_t)ks0 * 32 + csrc * 8;
  const size_t rsk = (size_t)128 * K;
  const int dstoff = tid * 8;

  int offA[8], offB[4];
  #pragma unroll
  for (int m = 0; m < 8; ++m) {
    int r = wm * 128 + m * 16 + lrow;
    offA[m] = r * 32 + ((c0 ^ ((r >> 1) & 3)) << 3);
  }
  #pragma unroll
  for (int n = 0; n < 4; ++n) {
    int r = wn * 64 + n * 16 + lrow;
    offB[n] = r * 32 + ((c0 ^ ((r >> 1) & 3)) << 3);
  }

#define STAGE_A(g) { int sg = ((g) < kunits) ? (g) : (kunits - 1);          \
    const u16* s_ = pAg + (size_t)sg * 32;                                   \
    u16* dp_ = lds + (((g) & 3) * 8192) + dstoff;                            \
    gload16(s_, dp_); gload16(s_ + rsk, dp_ + 4096); }
#define STAGE_B(g) { int sg = ((g) < kunits) ? (g) : (kunits - 1);          \
    const u16* s_ = pBg + (size_t)sg * 32;                                   \
    u16* dp_ = lds + 32768 + (((g) & 3) * 8192) + dstoff;                    \
    gload16(s_, dp_); gload16(s_ + rsk, dp_ + 4096); }

  f32x4 acc[8][4];
  #pragma unroll
  for (int m = 0; m < 8; ++m)
    #pragma unroll
    for (int n = 0; n < 4; ++n) acc[m][n] = f32x4{0.f, 0.f, 0.f, 0.f};

  // prologue: 7 granules (14 loads); vmcnt(6) forces A0,B0,A1,B1
  STAGE_A(0); STAGE_B(0); STAGE_A(1); STAGE_B(1); STAGE_A(2); STAGE_B(2); STAGE_B(3);
  asm volatile("s_waitcnt vmcnt(6)" ::: "memory");
  __builtin_amdgcn_s_barrier();

  bf16x8 ac0, ac1, ac2, ac3, an0, an1, an2, an3;
  bf16x8 bgc0, bgc1, bgc2, bgc3, bgn0, bgn1, bgn2, bgn3;

  // prime: P0's fragments (a[0-3] kk0, bg kk0 from slot 0)
  {
    const u16* As0_ = lds;
    const u16* Bs0_ = lds + 32768;
    ac0 = *reinterpret_cast<const bf16x8*>(As0_ + offA[0]);
    ac1 = *reinterpret_cast<const bf16x8*>(As0_ + offA[1]);
    ac2 = *reinterpret_cast<const bf16x8*>(As0_ + offA[2]);
    ac3 = *reinterpret_cast<const bf16x8*>(As0_ + offA[3]);
    bgc0 = *reinterpret_cast<const bf16x8*>(Bs0_ + offB[0]);
    bgc1 = *reinterpret_cast<const bf16x8*>(Bs0_ + offB[1]);
    bgc2 = *reinterpret_cast<const bf16x8*>(Bs0_ + offB[2]);
    bgc3 = *reinterpret_cast<const bf16x8*>(Bs0_ + offB[3]);
  }

  for (int tt = 0; tt < ftiles; ++tt) {
    const int g0 = tt << 1;
    const u16* As0 = lds + ((g0 & 3) * 8192);
    const u16* As1 = lds + (((g0 + 1) & 3) * 8192);
    const u16* Bs1 = lds + 32768 + (((g0 + 1) & 3) * 8192);
    const u16* As2 = lds + (((g0 + 2) & 3) * 8192);
    const u16* Bs2 = lds + 32768 + (((g0 + 2) & 3) * 8192);

    // ---- P0: MFMA m0-3 (ac x bgc, kk0); prefetch an = A[4-7] kk0
    __builtin_amdgcn_s_barrier();
    STAGE_A(g0 + 3);
    an0 = *reinterpret_cast<const bf16x8*>(As0 + offA[4]);
    an1 = *reinterpret_cast<const bf16x8*>(As0 + offA[5]);
    an2 = *reinterpret_cast<const bf16x8*>(As0 + offA[6]);
    an3 = *reinterpret_cast<const bf16x8*>(As0 + offA[7]);
    __builtin_amdgcn_sched_barrier(0);
    asm volatile("s_waitcnt lgkmcnt(4)" ::: "memory");
    __builtin_amdgcn_sched_barrier(0);
    __builtin_amdgcn_s_setprio(1);
    acc[0][0] = __builtin_amdgcn_mfma_f32_16x16x32_bf16(ac0, bgc0, acc[0][0], 0, 0, 0);
    acc[0][1] = __builtin_amdgcn_mfma_f32_16x16x32_bf16(ac0, bgc1, acc[0][1], 0, 0, 0);
    acc[0][2] = __builtin_amdgcn_mfma_f32_16x16x32_bf16(ac0, bgc2, acc[0][2], 0, 0, 0);
    acc[0][3] = __builtin_amdgcn_mfma_f32_16x16x32_bf16(ac0, bgc3, acc[0][3], 0, 0, 0);
    acc[1][0] = __builtin_amdgcn_mfma_f32_16x16x32_bf16(ac1, bgc0, acc[1][0], 0, 0, 0);
    acc[1][1] = __builtin_amdgcn_mfma_f32_16x16x32_bf16(ac1, bgc1, acc[1][1], 0, 0, 0);
    acc[1][2] = __builtin_amdgcn_mfma_f32_16x16x32_bf16(ac1, bgc2, acc[1][2], 0, 0, 0);
    acc[1][3] = __builtin_amdgcn_mfma_f32_16x16x32_bf16(ac1, bgc3, acc[1][3], 0, 0, 0);
    acc[2][0] = __builtin_amdgcn_mfma_f32_16x16x32_bf16(ac2, bgc0, acc[2][0], 0, 0, 0);
    acc[2][1] = __builtin_amdgcn_mfma_f32_16x16x32_bf16(ac2, bgc1, acc[2][1], 0, 0, 0);
    acc[2][2] = __builtin_amdgcn_mfma_f32_16x16x32_bf16(ac2, bgc2, acc[2][2], 0, 0, 0);
    acc[2][3] = __builtin_amdgcn_mfma_f32_16x16x32_bf16(ac2, bgc3, acc[2][3], 0, 0, 0);
    acc[3][0] = __builtin_amdgcn_mfma_f32_16x16x32_bf16(ac3, bgc0, acc[3][0], 0, 0, 0);
    acc[3][1] = __builtin_amdgcn_mfma_f32_16x16x32_bf16(ac3, bgc1, acc[3][1], 0, 0, 0);
    acc[3][2] = __builtin_amdgcn_mfma_f32_16x16x32_bf16(ac3, bgc2, acc[3][2], 0, 0, 0);
    acc[3][3] = __builtin_amdgcn_mfma_f32_16x16x32_bf16(ac3, bgc3, acc[3][3], 0, 0, 0);
    __builtin_amdgcn_s_setprio(0);
    __builtin_amdgcn_sched_barrier(0);

    // ---- P1: MFMA m4-7 (an x bgc, kk0); prefetch ac = A[0-3] kk1, bgn = B kk1
    __builtin_amdgcn_s_barrier();
    STAGE_B(g0 + 4);
    ac0 = *reinterpret_cast<const bf16x8*>(As1 + offA[0]);
    ac1 = *reinterpret_cast<const bf16x8*>(As1 + offA[1]);
    ac2 = *reinterpret_cast<const bf16x8*>(As1 + offA[2]);
    ac3 = *reinterpret_cast<const bf16x8*>(As1 + offA[3]);
    bgn0 = *reinterpret_cast<const bf16x8*>(Bs1 + offB[0]);
    bgn1 = *reinterpret_cast<const bf16x8*>(Bs1 + offB[1]);
    bgn2 = *reinterpret_cast<const bf16x8*>(Bs1 + offB[2]);
    bgn3 = *reinterpret_cast<const bf16x8*>(Bs1 + offB[3]);
    __builtin_amdgcn_sched_barrier(0);
    asm volatile("s_waitcnt lgkmcnt(8)" ::: "memory");
    __builtin_amdgcn_sched_barrier(0);
    __builtin_amdgcn_s_setprio(1);
    acc[4][0] = __builtin_amdgcn_mfma_f32_16x16x32_bf16(an0, bgc0, acc[4][0], 0, 0, 0);
    acc[4][1] = __builtin_amdgcn_mfma_f32_16x16x32_bf16(an0, bgc1, acc[4][1], 0, 0, 0);
    acc[4][2] = __builtin_amdgcn_mfma_f32_16x16x32_bf16(an0, bgc2, acc[4][2], 0, 0, 0);
    acc[4][3] = __builtin_amdgcn_mfma_f32_16x16x32_bf16(an0, bgc3, acc[4][3], 0, 0, 0);
    acc[5][0] = __builtin_amdgcn_mfma_f32_16x16x32_bf16(an1, bgc0, acc[5][0], 0, 0, 0);
    acc[5][1] = __builtin_amdgcn_mfma_f32_16x16x32_bf16(an1, bgc1, acc[5][1], 0, 0, 0);
    acc[5][2] = __builtin_amdgcn_mfma_f32_16x16x32_bf16(an1, bgc2, acc[5][2], 0, 0, 0);
    acc[5][3] = __builtin_amdgcn_mfma_f32_16x16x32_bf16(an1, bgc3, acc[5][3], 0, 0, 0);
    acc[6][0] = __builtin_amdgcn_mfma_f32_16x16x32_bf16(an2, bgc0, acc[6][0], 0, 0, 0);
    acc[6][1] = __builtin_amdgcn_mfma_f32_16x16x32_bf16(an2, bgc1, acc[6][1], 0, 0, 0);
    acc[6][2] = __builtin_amdgcn_mfma_f32_16x16x32_bf16(an2, bgc2, acc[6][2], 0, 0, 0);
    acc[6][3] = __builtin_amdgcn_mfma_f32_16x16x32_bf16(an2, bgc3, acc[6][3], 0, 0, 0);
    acc[7][0] = __builtin_amdgcn_mfma_f32_16x16x32_bf16(an3, bgc0, acc[7][0], 0, 0, 0);
    acc[7][1] = __builtin_amdgcn_mfma_f32_16x16x32_bf16(an3, bgc1, acc[7][1], 0, 0, 0);
    acc[7][2] = __builtin_amdgcn_mfma_f32_16x16x32_bf16(an3, bgc2, acc[7][2], 0, 0, 0);
    acc[7][3] = __builtin_amdgcn_mfma_f32_16x16x32_bf16(an3, bgc3, acc[7][3], 0, 0, 0);
    __builtin_amdgcn_s_setprio(0);
    __builtin_amdgcn_sched_barrier(0);

    // ---- P2: MFMA m0-3 (ac x bgn, kk1); prefetch an = A[4-7] kk1
    __builtin_amdgcn_s_barrier();
    STAGE_A(g0 + 4);
    an0 = *reinterpret_cast<const bf16x8*>(As1 + offA[4]);
    an1 = *reinterpret_cast<const bf16x8*>(As1 + offA[5]);
    an2 = *reinterpret_cast<const bf16x8*>(As1 + offA[6]);
    an3 = *reinterpret_cast<const bf16x8*>(As1 + offA[7]);
    __builtin_amdgcn_sched_barrier(0);
    asm volatile("s_waitcnt lgkmcnt(4)" ::: "memory");
    __builtin_amdgcn_sched_barrier(0);
    __builtin_amdgcn_s_setprio(1);
    acc[0][0] = __builtin_amdgcn_mfma_f32_16x16x32_bf16(ac0, bgn0, acc[0][0], 0, 0, 0);
    acc[0][1] = __builtin_amdgcn_mfma_f32_16x16x32_bf16(ac0, bgn1, acc[0][1], 0, 0, 0);
    acc[0][2] = __builtin_amdgcn_mfma_f32_16x16x32_bf16(ac0, bgn2, acc[0][2], 0, 0, 0);
    acc[0][3] = __builtin_amdgcn_mfma_f32_16x16x32_bf16(ac0, bgn3, acc[0][3], 0, 0, 0);
    acc[1][0] = __builtin_amdgcn_mfma_f32_16x16x32_bf16(ac1, bgn0, acc[1][0], 0, 0, 0);
    acc[1][1] = __builtin_amdgcn_mfma_f32_16x16x32_bf16(ac1, bgn1, acc[1][1], 0, 0, 0);
    acc[1][2] = __builtin_amdgcn_mfma_f32_16x16x32_bf16(ac1, bgn2, acc[1][2], 0, 0, 0);
    acc[1][3] = __builtin_amdgcn_mfma_f32_16x16x32_bf16(ac1, bgn3, acc[1][3], 0, 0, 0);
    acc[2][0] = __builtin_amdgcn_mfma_f32_16x16x32_bf16(ac2, bgn0, acc[2][0], 0, 0, 0);
    acc[2][1] = __builtin_amdgcn_mfma_f32_16x16x32_bf16(ac2, bgn1, acc[2][1], 0, 0, 0);
    acc[2][2] = __builtin_amdgcn_mfma_f32_16x16x32_bf16(ac2, bgn2, acc[2][2], 0, 0, 0);
    acc[2][3] = __builtin_amdgcn_mfma_f32_16x16x32_bf16(ac2, bgn3, acc[2][3], 0, 0, 0);
    acc[3][0] = __builtin_amdgcn_mfma_f32_16x16x32_bf16(ac3, bgn0, acc[3][0], 0, 0, 0);
    acc[3][1] = __builtin_amdgcn_mfma_f32_16x16x32_bf16(ac3, bgn1, acc[3][1], 0, 0, 0);
    acc[3][2] = __builtin_amdgcn_mfma_f32_16x16x32_bf16(ac3, bgn2, acc[3][2], 0, 0, 0);
    acc[3][3] = __builtin_amdgcn_mfma_f32_16x16x32_bf16(ac3, bgn3, acc[3][3], 0, 0, 0);
    __builtin_amdgcn_s_setprio(0);
    __builtin_amdgcn_sched_barrier(0);
    asm volatile("s_waitcnt vmcnt(6)" ::: "memory");   // force next-kk0 granules

    // ---- P3: MFMA m4-7 (an x bgn, kk1); prefetch ac/bgc = next tile kk0
    __builtin_amdgcn_s_barrier();
    STAGE_B(g0 + 5);
    ac0 = *reinterpret_cast<const bf16x8*>(As2 + offA[0]);
    ac1 = *reinterpret_cast<const bf16x8*>(As2 + offA[1]);
    ac2 = *reinterpret_cast<const bf16x8*>(As2 + offA[2]);
    ac3 = *reinterpret_cast<const bf16x8*>(As2 + offA[3]);
    bgc0 = *reinterpret_cast<const bf16x8*>(Bs2 + offB[0]);
    bgc1 = *reinterpret_cast<const bf16x8*>(Bs2 + offB[1]);
    bgc2 = *reinterpret_cast<const bf16x8*>(Bs2 + offB[2]);
    bgc3 = *reinterpret_cast<const bf16x8*>(Bs2 + offB[3]);
    __builtin_amdgcn_sched_barrier(0);
    asm volatile("s_waitcnt lgkmcnt(8)" ::: "memory");
    __builtin_amdgcn_sched_barrier(0);
    __builtin_amdgcn_s_setprio(1);
    acc[4][0] = __builtin_amdgcn_mfma_f32_16x16x32_bf16(an0, bgn0, acc[4][0], 0, 0, 0);
    acc[4][1] = __builtin_amdgcn_mfma_f32_16x16x32_bf16(an0, bgn1, acc[4][1], 0, 0, 0);
    acc[4][2] = __builtin_amdgcn_mfma_f32_16x16x32_bf16(an0, bgn2, acc[4][2], 0, 0, 0);
    acc[4][3] = __builtin_amdgcn_mfma_f32_16x16x32_bf16(an0, bgn3, acc[4][3], 0, 0, 0);
    acc[5][0] = __builtin_amdgcn_mfma_f32_16x16x32_bf16(an1, bgn0, acc[5][0], 0, 0, 0);
    acc[5][1] = __builtin_amdgcn_mfma_f32_16x16x32_bf16(an1, bgn1, acc[5][1], 0, 0, 0);
    acc[5][2] = __builtin_amdgcn_mfma_f32_16x16x32_bf16(an1, bgn2, acc[5][2], 0, 0, 0);
    acc[5][3] = __builtin_amdgcn_mfma_f32_16x16x32_bf16(an1, bgn3, acc[5][3], 0, 0, 0);
    acc[6][0] = __builtin_amdgcn_mfma_f32_16x16x32_bf16(an2, bgn0, acc[6][0], 0, 0, 0);
    acc[6][1] = __builtin_amdgcn_mfma_f32_16x16x32_bf16(an2, bgn1, acc[6][1], 0, 0, 0);
    acc[6][2] = __builtin_amdgcn_mfma_f32_16x16x32_bf16(an2, bgn2, acc[6][2], 0, 0, 0);
    acc[6][3] = __builtin_amdgcn_mfma_f32_16x16x32_bf16(an2, bgn3, acc[6][3], 0, 0, 0);
    acc[7][0] = __builtin_amdgcn_mfma_f32_16x16x32_bf16(an3, bgn0, acc[7][0], 0, 0, 0);
    acc[7][1] = __builtin_amdgcn_mfma_f32_16x16x32_bf16(an3, bgn1, acc[7][1], 0, 0, 0);
    acc[7][2] = __builtin_amdgcn_mfma_f32_16x16x32_bf16(an3, bgn2, acc[7][2], 0, 0, 0);
    acc[7][3] = __builtin_amdgcn_mfma_f32_16x16x32_bf16(an3, bgn3, acc[7][3], 0, 0, 0);
    __builtin_amdgcn_s_setprio(0);
    __builtin_amdgcn_sched_barrier(0);
    asm volatile("s_waitcnt vmcnt(6)" ::: "memory");   // force next-kk1 granules
  }

  if (kunits & 1) {
    asm volatile("s_waitcnt vmcnt(0)" ::: "memory");
    __builtin_amdgcn_s_barrier();
    const int g = kunits - 1;
    const u16* As = lds + ((g & 3) * 8192);
    const u16* Bs = lds + 32768 + ((g & 3) * 8192);
    bf16x8 tb0 = *reinterpret_cast<const bf16x8*>(Bs + offB[0]);
    bf16x8 tb1 = *reinterpret_cast<const bf16x8*>(Bs + offB[1]);
    bf16x8 tb2 = *reinterpret_cast<const bf16x8*>(Bs + offB[2]);
    bf16x8 tb3 = *reinterpret_cast<const bf16x8*>(Bs + offB[3]);
    #pragma unroll
    for (int m = 0; m < 8; ++m) {
      bf16x8 am = *reinterpret_cast<const bf16x8*>(As + offA[m]);
      acc[m][0] = __builtin_amdgcn_mfma_f32_16x16x32_bf16(am, tb0, acc[m][0], 0, 0, 0);
      acc[m][1] = __builtin_amdgcn_mfma_f32_16x16x32_bf16(am, tb1, acc[m][1], 0, 0, 0);
      acc[m][2] = __builtin_amdgcn_mfma_f32_16x16x32_bf16(am, tb2, acc[m][2], 0, 0, 0);
      acc[m][3] = __builtin_amdgcn_mfma_f32_16x16x32_bf16(am, tb3, acc[m][3], 0, 0, 0);
    }
  }
#undef STAGE_A
#undef STAGE_B

  float* C = Cp + (size_t)sb * M * N;
  #pragma unroll
  for (int m = 0; m < 8; ++m) {
    const int rb = mb * 256 + wm * 128 + m * 16 + (lane >> 4) * 4;
    #pragma unroll
    for (int n = 0; n < 4; ++n) {
      const int col = nb * 256 + wn * 64 + n * 16 + (lane & 15);
      #pragma unroll
      for (int j2 = 0; j2 < 4; ++j2)
        __builtin_nontemporal_store(acc[m][n][j2], &C[(size_t)(rb + j2) * N + col]);
    }
  }
}

// ---------------------------------------------------------------------------
// 128x128 m97-structure GEMM for the small layers 2/3
// ---------------------------------------------------------------------------
__global__ __launch_bounds__(256) void gemm_bf16(
    const u16* __restrict__ A, const u16* __restrict__ Bt,
    float* __restrict__ Cp, int M, int N, int K, int kps)
{
  __shared__ __align__(16) u16 lA[128 * 32];
  __shared__ __align__(16) u16 lB[128 * 32];
  const int tid = threadIdx.x;
  const int mb = blockIdx.x, nb = blockIdx.y, sb = blockIdx.z;
  const int w = tid >> 6, lane = tid & 63;
  const int wr = (w >> 1) * 64, wc = (w & 1) * 64;
  const int lrow = lane & 15, lko = (lane >> 4) * 8;

  f32x4 acc[4][4];
  #pragma unroll
  for (int m = 0; m < 4; ++m)
    #pragma unroll
    for (int n = 0; n < 4; ++n) acc[m][n] = f32x4{0.f, 0.f, 0.f, 0.f};

  const u16* Ab = A + (size_t)mb * 128 * K;
  const u16* Bb = Bt + (size_t)nb * 128 * K;
  const int r0 = tid >> 2, inn = (tid & 3) * 8;
  const int l0 = (tid & ~63) * 8, l1 = ((256 + tid) & ~63) * 8;

  const int ks1 = (sb + 1) * kps;
  for (int ks = sb * kps; ks < ks1; ++ks) {
    const int k0 = ks * 32;
    __syncthreads();
    gload16(Ab + (size_t)r0 * K + k0 + inn,        lA + l0);
    gload16(Ab + (size_t)(r0 + 64) * K + k0 + inn, lA + l1);
    gload16(Bb + (size_t)r0 * K + k0 + inn,        lB + l0);
    gload16(Bb + (size_t)(r0 + 64) * K + k0 + inn, lB + l1);
    __syncthreads();
    bf16x8 af[4], bg[4];
    #pragma unroll
    for (int m = 0; m < 4; ++m)
      af[m] = *reinterpret_cast<const bf16x8*>(&lA[(wr + m * 16 + lrow) * 32 + lko]);
    #pragma unroll
    for (int n = 0; n < 4; ++n)
      bg[n] = *reinterpret_cast<const bf16x8*>(&lB[(wc + n * 16 + lrow) * 32 + lko]);
    #pragma unroll
    for (int m = 0; m < 4; ++m)
      #pragma unroll
      for (int n = 0; n < 4; ++n)
        acc[m][n] = __builtin_amdgcn_mfma_f32_16x16x32_bf16(af[m], bg[n], acc[m][n], 0, 0, 0);
  }

  float* C = Cp + (size_t)sb * M * N;
  #pragma unroll
  for (int m = 0; m < 4; ++m) {
    const int rb = mb * 128 + wr + m * 16 + (lane >> 4) * 4;
    #pragma unroll
    for (int n = 0; n < 4; ++n) {
      const int col = nb * 128 + wc + n * 16 + (lane & 15);
      #pragma unroll
      for (int j = 0; j < 4; ++j)
        __builtin_nontemporal_store(acc[m][n][j], &C[(size_t)(rb + j) * N + col]);
    }
  }
}

// ---------------------------------------------------------------------------
// Split-K reduce + bias + relu -> bf16, vectorized
// ---------------------------------------------------------------------------
__global__ __launch_bounds__(256) void reduce_bias_relu_bf16(
    const float* __restrict__ part, int S, size_t MN,
    const float* __restrict__ bias, int nmask, u16* __restrict__ out)
{
  const size_t n8 = MN >> 3;
  for (size_t i8 = blockIdx.x * 256ull + threadIdx.x; i8 < n8; i8 += (size_t)gridDim.x * 256) {
    const size_t base = i8 * 8;
    f32x4 lo = {0.f, 0.f, 0.f, 0.f}, hi = {0.f, 0.f, 0.f, 0.f};
    for (int k = 0; k < S; ++k) {
      const float* p = part + (size_t)k * MN + base;
      f32x4 a = __builtin_nontemporal_load(reinterpret_cast<const f32x4*>(p));
      f32x4 b = __builtin_nontemporal_load(reinterpret_cast<const f32x4*>(p + 4));
      lo += a; hi += b;
    }
    const int bb = (int)(base & (size_t)nmask);
    const f32x4 b0 = *reinterpret_cast<const f32x4*>(bias + bb);
    const f32x4 b1 = *reinterpret_cast<const f32x4*>(bias + bb + 4);
    u16x8 v;
    #pragma unroll
    for (int e = 0; e < 4; ++e) v[e] = f2bf(fmaxf(lo[e] + b0[e], 0.f));
    #pragma unroll
    for (int e = 0; e < 4; ++e) v[4 + e] = f2bf(fmaxf(hi[e] + b1[e], 0.f));
    *reinterpret_cast<u16x8*>(out + base) = v;
  }
}

// ---------------------------------------------------------------------------
// Merged layer-3 reduce + bias + relu + final dot
// ---------------------------------------------------------------------------
__global__ __launch_bounds__(256) void reduce3_final(
    const float* __restrict__ part, const float* __restrict__ bd3,
    const float* __restrict__ Wout, const float* __restrict__ bout,
    float* __restrict__ out)
{
  const int row = blockIdx.x * 4 + (threadIdx.x >> 6);
  const int lane = threadIdx.x & 63;
  const size_t MN = (size_t)BATCH * HD3;
  const size_t base = (size_t)row * HD3;
  float s = 0.f;
  #pragma unroll
  for (int i = 0; i < 4; ++i) {
    const int e = lane + i * 64;
    float v = 0.f;
    #pragma unroll
    for (int k = 0; k < 4; ++k)
      v += __builtin_nontemporal_load(&part[(size_t)k * MN + base + e]);
    v = fmaxf(v + bd3[e], 0.f);
    s += v * Wout[e];
  }
  #pragma unroll
  for (int off = 32; off; off >>= 1) s += __shfl_down(s, off, 64);
  if (lane == 0) out[row] = s + bout[0];
}

// ---------------------------------------------------------------------------
extern "C" void kernel_launch(void* const* d_in, const int* in_sizes, int n_in,
                              void* d_out, int out_size, void* d_ws, size_t ws_size,
                              hipStream_t stream)
{
  const int*   cat    = (const int*)  d_in[0];
  const float* num    = (const float*)d_in[1];
  const float* tables = (const float*)d_in[2];
  const float* nemb   = (const float*)d_in[3];
  const float* Wse1   = (const float*)d_in[4];
  const float* Wse2   = (const float*)d_in[5];
  const float* Wbil   = (const float*)d_in[6];
  const float* Wd1    = (const float*)d_in[7];
  const float* bd1    = (const float*)d_in[8];
  const float* Wd2    = (const float*)d_in[9];
  const float* bd2    = (const float*)d_in[10];
  const float* Wd3    = (const float*)d_in[11];
  const float* bd3    = (const float*)d_in[12];
  const float* Wout   = (const float*)d_in[13];
  const float* bout   = (const float*)d_in[14];

  char* ws = (char*)d_ws;
  u16*   hid  = (u16*)  (ws + 0ull);           // 194,248,704  bf16 [4096][23712]
  u16*   W1t  = (u16*)  (ws + 194248704ull);   //  48,562,176  bf16 [1024][23712]
  float* part = (float*)(ws + 242810880ull);   //  67,108,864  f32 splitK partials
  u16*   W2t  = (u16*)  (ws + 309919744ull);   //   1,048,576
  u16*   W3t  = (u16*)  (ws + 310968320ull);   //     262,144
  u16*   h1b  = (u16*)  (ws + 0ull);           // dead-hid reuse
  u16*   h2b  = (u16*)  (ws + 8388608ull);

  transpose_all<<<741 * 32 + 512 + 128, 256, 0, stream>>>(Wd1, Wd2, Wd3, W1t, W2t, W3t);
  fuse_front<<<BATCH / 2, 256, 0, stream>>>(cat, num, tables, nemb, Wse1, Wse2, Wbil, hid);

  gemm8p_bf16<<<256, 512, 0, stream>>>(hid, W1t, part, BATCH, HD1, KHID, 741, 186);
  reduce_bias_relu_bf16<<<2048, 256, 0, stream>>>(part, 4, (size_t)BATCH * HD1, bd1, HD1 - 1, h1b);

  gemm_bf16<<<dim3(BATCH / 128, HD2 / 128, 2), 256, 0, stream>>>(h1b, W2t, part, BATCH, HD2, HD1, 16);
  reduce_bias_relu_bf16<<<1024, 256, 0, stream>>>(part, 2, (size_t)BATCH * HD2, bd2, HD2 - 1, h2b);

  gemm_bf16<<<dim3(BATCH / 128, HD3 / 128, 4), 256, 0, stream>>>(h2b, W3t, part, BATCH, HD3, HD2, 4);
  reduce3_final<<<BATCH / 4, 256, 0, stream>>>(part, bd3, Wout, bout, (float*)d_out);
}

// Round 12
// 340.220 us; speedup vs baseline: 1.0055x; 1.0055x over previous
//
#include <hip/hip_runtime.h>

typedef unsigned short u16;
typedef __attribute__((ext_vector_type(8))) __bf16 bf16x8;
typedef __attribute__((ext_vector_type(4))) float f32x4;
typedef __attribute__((ext_vector_type(4))) unsigned short u16x4;
typedef __attribute__((ext_vector_type(8))) unsigned short u16x8;

#define NF    39
#define NNUM  13
#define NCAT  26
#define VOC   100000
#define NPAIR 741
#define KHID  23712   /* 2*741*16 */
#define BATCH 4096
#define HD1   1024
#define HD2   512
#define HD3   256

__device__ __forceinline__ u16 f2bf(float f) {
  unsigned u = __builtin_bit_cast(unsigned, f);
  return (u16)((u + 0x7fffu + ((u >> 16) & 1u)) >> 16);   // RNE
}

__device__ __forceinline__ void gload16(const void* g, void* l) {
  __builtin_amdgcn_global_load_lds((const __attribute__((address_space(1))) void*)g,
                                   (__attribute__((address_space(3))) void*)l, 16, 0, 0);
}

// ---------------------------------------------------------------------------
// prep_all: merged front-end (blocks 0..2047, 2 rows each) + weight
// transposes (blocks 2048..). Outputs independent (hid vs W1t/W2t/W3t);
// heavy fuse blocks get low blockIdx so they dispatch first and the light
// transpose blocks backfill. LDS unioned.
// ---------------------------------------------------------------------------
union PrepShared {
  struct {
    float xs[2][NF][16];
    float wb[NF][16][16];
    float pr[2][NF][16];
    float Zs[2][NF], Ts[2][NNUM], As[2][NF];
    unsigned char pis[NPAIR], pjs[NPAIR];
  } f;
  struct { float t[32][33]; } tr;
};

__global__ __launch_bounds__(256) void prep_all(
    const int* __restrict__ cat, const float* __restrict__ num,
    const float* __restrict__ tables, const float* __restrict__ nemb,
    const float* __restrict__ Wse1, const float* __restrict__ Wse2,
    const float* __restrict__ Wbil, u16* __restrict__ hid,
    const float* __restrict__ Wd1, const float* __restrict__ Wd2,
    const float* __restrict__ Wd3, u16* __restrict__ W1t,
    u16* __restrict__ W2t, u16* __restrict__ W3t)
{
  __shared__ PrepShared sh;
  const int bid = blockIdx.x;
  const int tid = threadIdx.x;

  if (bid < BATCH / 2) {
    // ---------------- front end, 2 rows ----------------
    const int b0 = bid * 2;

    for (int i = tid; i < NF * 64; i += 256)
      ((f32x4*)sh.f.wb)[i] = ((const f32x4*)Wbil)[i];

    for (int t = tid; t < 2 * NNUM * 16; t += 256) {
      int r = t / (NNUM * 16), t2 = t % (NNUM * 16);
      int f = t2 >> 4, e = t2 & 15;
      sh.f.xs[r][f][e] = num[(b0 + r) * NNUM + f] * nemb[t2];
    }
    for (int t = tid; t < 2 * NCAT * 16; t += 256) {
      int r = t / (NCAT * 16), t2 = t % (NCAT * 16);
      int c = t2 >> 4, e = t2 & 15;
      int cv = cat[(b0 + r) * NCAT + c];
      sh.f.xs[r][NNUM + c][e] = tables[((size_t)c * VOC + cv) * 16 + e];
    }
    for (int p = tid; p < NPAIR; p += 256) {
      int i = 0, rs = 0;
      while (p >= rs + (NF - 1 - i)) { rs += NF - 1 - i; ++i; }
      sh.f.pis[p] = (unsigned char)i;
      sh.f.pjs[p] = (unsigned char)(i + 1 + (p - rs));
    }
    __syncthreads();

    if (tid < 2 * NF) {
      int r = tid / NF, f = tid % NF;
      float s = 0.f;
      #pragma unroll
      for (int e = 0; e < 16; ++e) s += sh.f.xs[r][f][e];
      sh.f.Zs[r][f] = s * (1.f / 16.f);
    }
    __syncthreads();
    if (tid < 2 * NNUM) {
      int r = tid / NNUM, o = tid % NNUM;
      float s = 0.f;
      for (int f = 0; f < NF; ++f) s += sh.f.Zs[r][f] * Wse1[f * NNUM + o];
      sh.f.Ts[r][o] = fmaxf(s, 0.f);
    }
    __syncthreads();
    if (tid < 2 * NF) {
      int r = tid / NF, f = tid % NF;
      float s = 0.f;
      for (int q = 0; q < NNUM; ++q) s += sh.f.Ts[r][q] * Wse2[q * NF + f];
      sh.f.As[r][f] = fmaxf(s, 0.f);
    }
    for (int t = tid; t < 2 * NF * 16; t += 256) {
      int r = t / (NF * 16), t2 = t % (NF * 16);
      int f = t2 >> 4, d = t2 & 15;
      float s = 0.f;
      #pragma unroll
      for (int e = 0; e < 16; ++e) s += sh.f.xs[r][f][e] * sh.f.wb[f][e][d];
      sh.f.pr[r][f][d] = s;
    }
    __syncthreads();

    for (int idx = tid; idx < 2 * NPAIR * 2; idx += 256) {
      const int r = idx / (NPAIR * 2), idx2 = idx % (NPAIR * 2);
      const int p = idx2 >> 1, e0 = (idx2 & 1) * 8;
      const int i = sh.f.pis[p], j = sh.f.pjs[p];
      const float aa = sh.f.As[r][i] * sh.f.As[r][j];
      u16* hr = hid + (size_t)(b0 + r) * KHID;
      u16x8 vb, vs;
      #pragma unroll
      for (int e = 0; e < 8; ++e) {
        float bv = sh.f.pr[r][i][e0 + e] * sh.f.xs[r][j][e0 + e];
        vb[e] = f2bf(bv);
        vs[e] = f2bf(aa * bv);
      }
      *reinterpret_cast<u16x8*>(hr + NPAIR * 16 + p * 16 + e0) = vb;
      *reinterpret_cast<u16x8*>(hr + p * 16 + e0) = vs;
    }
    return;
  }

  // ---------------- weight transposes ----------------
  const int tb = bid - BATCH / 2;
  const float* in; u16* out; int K, N, kb, nb;
  if (tb < 741 * 32)            { in = Wd1; out = W1t; K = KHID; N = HD1; kb = tb % 741; nb = tb / 741; }
  else if (tb < 741 * 32 + 512) { int r = tb - 741 * 32; in = Wd2; out = W2t; K = HD1; N = HD2; kb = r % 32; nb = r / 32; }
  else                          { int r = tb - 741 * 32 - 512; in = Wd3; out = W3t; K = HD2; N = HD3; kb = r % 16; nb = r / 16; }

  const int k0 = kb * 32, n0 = nb * 32;
  const int c = tid & 31, r = tid >> 5;
  #pragma unroll
  for (int it = 0; it < 4; ++it)
    sh.tr.t[r + it * 8][c] = in[(size_t)(k0 + r + it * 8) * N + n0 + c];
  __syncthreads();
  const int n = tid >> 3, kq = (tid & 7) * 4;
  u16x4 v;
  #pragma unroll
  for (int q = 0; q < 4; ++q) v[q] = f2bf(sh.tr.t[kq + q][n]);
  *reinterpret_cast<u16x4*>(out + (size_t)(n0 + n) * K + k0 + kq) = v;
}

// ---------------------------------------------------------------------------
// 256x256 8-wave m201-style fine-phase GEMM (round-10 benched best: 203-207us,
// VGPR 92). Per-tile 4 phases of 16 MFMA; single per-tile vmcnt(6) at P3 end;
// prologue vmcnt(6) forces A0,B0,A1,B1. Slot write-after-read safety is
// barrier-carried. absmax canary 2.980232e-08.
// ---------------------------------------------------------------------------
__global__ __launch_bounds__(512, 2) void gemm8p_bf16(
    const u16* __restrict__ A, const u16* __restrict__ Bt,
    float* __restrict__ Cp, int M, int N, int K, int totku, int kpb)
{
  __shared__ __align__(16) u16 lds[65536];   // A slots @0, B slots @32768

  const int tid = threadIdx.x;
  const int wid = tid >> 6, lane = tid & 63;

  const int d = blockIdx.x;
  const int x = d & 7, jj = d >> 3;
  const int mb = ((x & 3) << 2) | (jj & 3);
  const int nb = (jj >> 2) & 3;
  const int sb = ((x >> 2) << 1) | (jj >> 4);

  const int ks0 = sb * kpb;
  const int kunits = (totku - ks0 < kpb) ? (totku - ks0) : kpb;
  const int ftiles = kunits >> 1;

  const int wm = wid >> 2, wn = wid & 3;
  const int lrow = lane & 15, c0 = lane >> 4;

  const int rr = tid >> 2, cc = tid & 3, csrc = cc ^ ((rr >> 1) & 3);
  const u16* pAg = A  + (size_t)((size_t)mb * 256 + rr) * K + (size_t)ks0 * 32 + csrc * 8;
  const u16* pBg = Bt + (size_t)((size_t)nb * 256 + rr) * K + (size_t)ks0 * 32 + csrc * 8;
  const size_t rsk = (size_t)128 * K;
  const int dstoff = tid * 8;

  int offA[8], offB[4];
  #pragma unroll
  for (int m = 0; m < 8; ++m) {
    int r = wm * 128 + m * 16 + lrow;
    offA[m] = r * 32 + ((c0 ^ ((r >> 1) & 3)) << 3);
  }
  #pragma unroll
  for (int n = 0; n < 4; ++n) {
    int r = wn * 64 + n * 16 + lrow;
    offB[n] = r * 32 + ((c0 ^ ((r >> 1) & 3)) << 3);
  }

#define STAGE_A(g) { int sg = ((g) < kunits) ? (g) : (kunits - 1);          \
    const u16* s_ = pAg + (size_t)sg * 32;                                   \
    u16* dp_ = lds + (((g) & 3) * 8192) + dstoff;                            \
    gload16(s_, dp_); gload16(s_ + rsk, dp_ + 4096); }
#define STAGE_B(g) { int sg = ((g) < kunits) ? (g) : (kunits - 1);          \
    const u16* s_ = pBg + (size_t)sg * 32;                                   \
    u16* dp_ = lds + 32768 + (((g) & 3) * 8192) + dstoff;                    \
    gload16(s_, dp_); gload16(s_ + rsk, dp_ + 4096); }

  f32x4 acc[8][4];
  #pragma unroll
  for (int m = 0; m < 8; ++m)
    #pragma unroll
    for (int n = 0; n < 4; ++n) acc[m][n] = f32x4{0.f, 0.f, 0.f, 0.f};

  STAGE_A(0); STAGE_B(0); STAGE_A(1); STAGE_B(1); STAGE_A(2); STAGE_B(2); STAGE_B(3);
  asm volatile("s_waitcnt vmcnt(6)" ::: "memory");   // forces A0,B0,A1,B1
  __builtin_amdgcn_s_barrier();

  bf16x8 a0, a1, a2, a3, bg0, bg1, bg2, bg3;

  for (int tt = 0; tt < ftiles; ++tt) {
    const int g0 = tt << 1;
    const u16* As0 = lds + ((g0 & 3) * 8192);
    const u16* As1 = lds + (((g0 + 1) & 3) * 8192);
    const u16* Bs0 = lds + 32768 + ((g0 & 3) * 8192);
    const u16* Bs1 = lds + 32768 + (((g0 + 1) & 3) * 8192);

    // ---- P0: af(m0-3,kk0)+bg(kk0); stage A(g0+3)
    a0 = *reinterpret_cast<const bf16x8*>(As0 + offA[0]);
    a1 = *reinterpret_cast<const bf16x8*>(As0 + offA[1]);
    a2 = *reinterpret_cast<const bf16x8*>(As0 + offA[2]);
    a3 = *reinterpret_cast<const bf16x8*>(As0 + offA[3]);
    bg0 = *reinterpret_cast<const bf16x8*>(Bs0 + offB[0]);
    bg1 = *reinterpret_cast<const bf16x8*>(Bs0 + offB[1]);
    bg2 = *reinterpret_cast<const bf16x8*>(Bs0 + offB[2]);
    bg3 = *reinterpret_cast<const bf16x8*>(Bs0 + offB[3]);
    STAGE_A(g0 + 3);
    __builtin_amdgcn_sched_barrier(0);
    __builtin_amdgcn_s_barrier();
    asm volatile("s_waitcnt lgkmcnt(0)" ::: "memory");
    __builtin_amdgcn_sched_barrier(0);
    __builtin_amdgcn_s_setprio(1);
    acc[0][0] = __builtin_amdgcn_mfma_f32_16x16x32_bf16(a0, bg0, acc[0][0], 0, 0, 0);
    acc[0][1] = __builtin_amdgcn_mfma_f32_16x16x32_bf16(a0, bg1, acc[0][1], 0, 0, 0);
    acc[0][2] = __builtin_amdgcn_mfma_f32_16x16x32_bf16(a0, bg2, acc[0][2], 0, 0, 0);
    acc[0][3] = __builtin_amdgcn_mfma_f32_16x16x32_bf16(a0, bg3, acc[0][3], 0, 0, 0);
    acc[1][0] = __builtin_amdgcn_mfma_f32_16x16x32_bf16(a1, bg0, acc[1][0], 0, 0, 0);
    acc[1][1] = __builtin_amdgcn_mfma_f32_16x16x32_bf16(a1, bg1, acc[1][1], 0, 0, 0);
    acc[1][2] = __builtin_amdgcn_mfma_f32_16x16x32_bf16(a1, bg2, acc[1][2], 0, 0, 0);
    acc[1][3] = __builtin_amdgcn_mfma_f32_16x16x32_bf16(a1, bg3, acc[1][3], 0, 0, 0);
    acc[2][0] = __builtin_amdgcn_mfma_f32_16x16x32_bf16(a2, bg0, acc[2][0], 0, 0, 0);
    acc[2][1] = __builtin_amdgcn_mfma_f32_16x16x32_bf16(a2, bg1, acc[2][1], 0, 0, 0);
    acc[2][2] = __builtin_amdgcn_mfma_f32_16x16x32_bf16(a2, bg2, acc[2][2], 0, 0, 0);
    acc[2][3] = __builtin_amdgcn_mfma_f32_16x16x32_bf16(a2, bg3, acc[2][3], 0, 0, 0);
    acc[3][0] = __builtin_amdgcn_mfma_f32_16x16x32_bf16(a3, bg0, acc[3][0], 0, 0, 0);
    acc[3][1] = __builtin_amdgcn_mfma_f32_16x16x32_bf16(a3, bg1, acc[3][1], 0, 0, 0);
    acc[3][2] = __builtin_amdgcn_mfma_f32_16x16x32_bf16(a3, bg2, acc[3][2], 0, 0, 0);
    acc[3][3] = __builtin_amdgcn_mfma_f32_16x16x32_bf16(a3, bg3, acc[3][3], 0, 0, 0);
    __builtin_amdgcn_s_setprio(0);
    __builtin_amdgcn_sched_barrier(0);
    __builtin_amdgcn_s_barrier();

    // ---- P1: af(m4-7,kk0); stage B(g0+4)
    a0 = *reinterpret_cast<const bf16x8*>(As0 + offA[4]);
    a1 = *reinterpret_cast<const bf16x8*>(As0 + offA[5]);
    a2 = *reinterpret_cast<const bf16x8*>(As0 + offA[6]);
    a3 = *reinterpret_cast<const bf16x8*>(As0 + offA[7]);
    STAGE_B(g0 + 4);
    __builtin_amdgcn_sched_barrier(0);
    __builtin_amdgcn_s_barrier();
    asm volatile("s_waitcnt lgkmcnt(0)" ::: "memory");
    __builtin_amdgcn_sched_barrier(0);
    __builtin_amdgcn_s_setprio(1);
    acc[4][0] = __builtin_amdgcn_mfma_f32_16x16x32_bf16(a0, bg0, acc[4][0], 0, 0, 0);
    acc[4][1] = __builtin_amdgcn_mfma_f32_16x16x32_bf16(a0, bg1, acc[4][1], 0, 0, 0);
    acc[4][2] = __builtin_amdgcn_mfma_f32_16x16x32_bf16(a0, bg2, acc[4][2], 0, 0, 0);
    acc[4][3] = __builtin_amdgcn_mfma_f32_16x16x32_bf16(a0, bg3, acc[4][3], 0, 0, 0);
    acc[5][0] = __builtin_amdgcn_mfma_f32_16x16x32_bf16(a1, bg0, acc[5][0], 0, 0, 0);
    acc[5][1] = __builtin_amdgcn_mfma_f32_16x16x32_bf16(a1, bg1, acc[5][1], 0, 0, 0);
    acc[5][2] = __builtin_amdgcn_mfma_f32_16x16x32_bf16(a1, bg2, acc[5][2], 0, 0, 0);
    acc[5][3] = __builtin_amdgcn_mfma_f32_16x16x32_bf16(a1, bg3, acc[5][3], 0, 0, 0);
    acc[6][0] = __builtin_amdgcn_mfma_f32_16x16x32_bf16(a2, bg0, acc[6][0], 0, 0, 0);
    acc[6][1] = __builtin_amdgcn_mfma_f32_16x16x32_bf16(a2, bg1, acc[6][1], 0, 0, 0);
    acc[6][2] = __builtin_amdgcn_mfma_f32_16x16x32_bf16(a2, bg2, acc[6][2], 0, 0, 0);
    acc[6][3] = __builtin_amdgcn_mfma_f32_16x16x32_bf16(a2, bg3, acc[6][3], 0, 0, 0);
    acc[7][0] = __builtin_amdgcn_mfma_f32_16x16x32_bf16(a3, bg0, acc[7][0], 0, 0, 0);
    acc[7][1] = __builtin_amdgcn_mfma_f32_16x16x32_bf16(a3, bg1, acc[7][1], 0, 0, 0);
    acc[7][2] = __builtin_amdgcn_mfma_f32_16x16x32_bf16(a3, bg2, acc[7][2], 0, 0, 0);
    acc[7][3] = __builtin_amdgcn_mfma_f32_16x16x32_bf16(a3, bg3, acc[7][3], 0, 0, 0);
    __builtin_amdgcn_s_setprio(0);
    __builtin_amdgcn_sched_barrier(0);
    __builtin_amdgcn_s_barrier();

    // ---- P2: af(m0-3,kk1)+bg(kk1); stage A(g0+4)
    a0 = *reinterpret_cast<const bf16x8*>(As1 + offA[0]);
    a1 = *reinterpret_cast<const bf16x8*>(As1 + offA[1]);
    a2 = *reinterpret_cast<const bf16x8*>(As1 + offA[2]);
    a3 = *reinterpret_cast<const bf16x8*>(As1 + offA[3]);
    bg0 = *reinterpret_cast<const bf16x8*>(Bs1 + offB[0]);
    bg1 = *reinterpret_cast<const bf16x8*>(Bs1 + offB[1]);
    bg2 = *reinterpret_cast<const bf16x8*>(Bs1 + offB[2]);
    bg3 = *reinterpret_cast<const bf16x8*>(Bs1 + offB[3]);
    STAGE_A(g0 + 4);
    __builtin_amdgcn_sched_barrier(0);
    __builtin_amdgcn_s_barrier();
    asm volatile("s_waitcnt lgkmcnt(0)" ::: "memory");
    __builtin_amdgcn_sched_barrier(0);
    __builtin_amdgcn_s_setprio(1);
    acc[0][0] = __builtin_amdgcn_mfma_f32_16x16x32_bf16(a0, bg0, acc[0][0], 0, 0, 0);
    acc[0][1] = __builtin_amdgcn_mfma_f32_16x16x32_bf16(a0, bg1, acc[0][1], 0, 0, 0);
    acc[0][2] = __builtin_amdgcn_mfma_f32_16x16x32_bf16(a0, bg2, acc[0][2], 0, 0, 0);
    acc[0][3] = __builtin_amdgcn_mfma_f32_16x16x32_bf16(a0, bg3, acc[0][3], 0, 0, 0);
    acc[1][0] = __builtin_amdgcn_mfma_f32_16x16x32_bf16(a1, bg0, acc[1][0], 0, 0, 0);
    acc[1][1] = __builtin_amdgcn_mfma_f32_16x16x32_bf16(a1, bg1, acc[1][1], 0, 0, 0);
    acc[1][2] = __builtin_amdgcn_mfma_f32_16x16x32_bf16(a1, bg2, acc[1][2], 0, 0, 0);
    acc[1][3] = __builtin_amdgcn_mfma_f32_16x16x32_bf16(a1, bg3, acc[1][3], 0, 0, 0);
    acc[2][0] = __builtin_amdgcn_mfma_f32_16x16x32_bf16(a2, bg0, acc[2][0], 0, 0, 0);
    acc[2][1] = __builtin_amdgcn_mfma_f32_16x16x32_bf16(a2, bg1, acc[2][1], 0, 0, 0);
    acc[2][2] = __builtin_amdgcn_mfma_f32_16x16x32_bf16(a2, bg2, acc[2][2], 0, 0, 0);
    acc[2][3] = __builtin_amdgcn_mfma_f32_16x16x32_bf16(a2, bg3, acc[2][3], 0, 0, 0);
    acc[3][0] = __builtin_amdgcn_mfma_f32_16x16x32_bf16(a3, bg0, acc[3][0], 0, 0, 0);
    acc[3][1] = __builtin_amdgcn_mfma_f32_16x16x32_bf16(a3, bg1, acc[3][1], 0, 0, 0);
    acc[3][2] = __builtin_amdgcn_mfma_f32_16x16x32_bf16(a3, bg2, acc[3][2], 0, 0, 0);
    acc[3][3] = __builtin_amdgcn_mfma_f32_16x16x32_bf16(a3, bg3, acc[3][3], 0, 0, 0);
    __builtin_amdgcn_s_setprio(0);
    __builtin_amdgcn_sched_barrier(0);
    __builtin_amdgcn_s_barrier();

    // ---- P3: af(m4-7,kk1); stage B(g0+5); single per-tile vmcnt(6)
    a0 = *reinterpret_cast<const bf16x8*>(As1 + offA[4]);
    a1 = *reinterpret_cast<const bf16x8*>(As1 + offA[5]);
    a2 = *reinterpret_cast<const bf16x8*>(As1 + offA[6]);
    a3 = *reinterpret_cast<const bf16x8*>(As1 + offA[7]);
    STAGE_B(g0 + 5);
    __builtin_amdgcn_sched_barrier(0);
    __builtin_amdgcn_s_barrier();
    asm volatile("s_waitcnt lgkmcnt(0)" ::: "memory");
    __builtin_amdgcn_sched_barrier(0);
    __builtin_amdgcn_s_setprio(1);
    acc[4][0] = __builtin_amdgcn_mfma_f32_16x16x32_bf16(a0, bg0, acc[4][0], 0, 0, 0);
    acc[4][1] = __builtin_amdgcn_mfma_f32_16x16x32_bf16(a0, bg1, acc[4][1], 0, 0, 0);
    acc[4][2] = __builtin_amdgcn_mfma_f32_16x16x32_bf16(a0, bg2, acc[4][2], 0, 0, 0);
    acc[4][3] = __builtin_amdgcn_mfma_f32_16x16x32_bf16(a0, bg3, acc[4][3], 0, 0, 0);
    acc[5][0] = __builtin_amdgcn_mfma_f32_16x16x32_bf16(a1, bg0, acc[5][0], 0, 0, 0);
    acc[5][1] = __builtin_amdgcn_mfma_f32_16x16x32_bf16(a1, bg1, acc[5][1], 0, 0, 0);
    acc[5][2] = __builtin_amdgcn_mfma_f32_16x16x32_bf16(a1, bg2, acc[5][2], 0, 0, 0);
    acc[5][3] = __builtin_amdgcn_mfma_f32_16x16x32_bf16(a1, bg3, acc[5][3], 0, 0, 0);
    acc[6][0] = __builtin_amdgcn_mfma_f32_16x16x32_bf16(a2, bg0, acc[6][0], 0, 0, 0);
    acc[6][1] = __builtin_amdgcn_mfma_f32_16x16x32_bf16(a2, bg1, acc[6][1], 0, 0, 0);
    acc[6][2] = __builtin_amdgcn_mfma_f32_16x16x32_bf16(a2, bg2, acc[6][2], 0, 0, 0);
    acc[6][3] = __builtin_amdgcn_mfma_f32_16x16x32_bf16(a2, bg3, acc[6][3], 0, 0, 0);
    acc[7][0] = __builtin_amdgcn_mfma_f32_16x16x32_bf16(a3, bg0, acc[7][0], 0, 0, 0);
    acc[7][1] = __builtin_amdgcn_mfma_f32_16x16x32_bf16(a3, bg1, acc[7][1], 0, 0, 0);
    acc[7][2] = __builtin_amdgcn_mfma_f32_16x16x32_bf16(a3, bg2, acc[7][2], 0, 0, 0);
    acc[7][3] = __builtin_amdgcn_mfma_f32_16x16x32_bf16(a3, bg3, acc[7][3], 0, 0, 0);
    __builtin_amdgcn_s_setprio(0);
    __builtin_amdgcn_sched_barrier(0);
    asm volatile("s_waitcnt vmcnt(6)" ::: "memory");
    __builtin_amdgcn_s_barrier();
  }

  if (kunits & 1) {
    asm volatile("s_waitcnt vmcnt(0)" ::: "memory");
    __builtin_amdgcn_s_barrier();
    const int g = kunits - 1;
    const u16* As = lds + ((g & 3) * 8192);
    const u16* Bs = lds + 32768 + ((g & 3) * 8192);
    bg0 = *reinterpret_cast<const bf16x8*>(Bs + offB[0]);
    bg1 = *reinterpret_cast<const bf16x8*>(Bs + offB[1]);
    bg2 = *reinterpret_cast<const bf16x8*>(Bs + offB[2]);
    bg3 = *reinterpret_cast<const bf16x8*>(Bs + offB[3]);
    #pragma unroll
    for (int m = 0; m < 8; ++m) {
      bf16x8 am = *reinterpret_cast<const bf16x8*>(As + offA[m]);
      acc[m][0] = __builtin_amdgcn_mfma_f32_16x16x32_bf16(am, bg0, acc[m][0], 0, 0, 0);
      acc[m][1] = __builtin_amdgcn_mfma_f32_16x16x32_bf16(am, bg1, acc[m][1], 0, 0, 0);
      acc[m][2] = __builtin_amdgcn_mfma_f32_16x16x32_bf16(am, bg2, acc[m][2], 0, 0, 0);
      acc[m][3] = __builtin_amdgcn_mfma_f32_16x16x32_bf16(am, bg3, acc[m][3], 0, 0, 0);
    }
  }
#undef STAGE_A
#undef STAGE_B

  float* C = Cp + (size_t)sb * M * N;
  #pragma unroll
  for (int m = 0; m < 8; ++m) {
    const int rb = mb * 256 + wm * 128 + m * 16 + (lane >> 4) * 4;
    #pragma unroll
    for (int n = 0; n < 4; ++n) {
      const int col = nb * 256 + wn * 64 + n * 16 + (lane & 15);
      #pragma unroll
      for (int j2 = 0; j2 < 4; ++j2)
        __builtin_nontemporal_store(acc[m][n][j2], &C[(size_t)(rb + j2) * N + col]);
    }
  }
}

// ---------------------------------------------------------------------------
// 128x128 m97-structure GEMM for the small layers 2/3
// ---------------------------------------------------------------------------
__global__ __launch_bounds__(256) void gemm_bf16(
    const u16* __restrict__ A, const u16* __restrict__ Bt,
    float* __restrict__ Cp, int M, int N, int K, int kps)
{
  __shared__ __align__(16) u16 lA[128 * 32];
  __shared__ __align__(16) u16 lB[128 * 32];
  const int tid = threadIdx.x;
  const int mb = blockIdx.x, nb = blockIdx.y, sb = blockIdx.z;
  const int w = tid >> 6, lane = tid & 63;
  const int wr = (w >> 1) * 64, wc = (w & 1) * 64;
  const int lrow = lane & 15, lko = (lane >> 4) * 8;

  f32x4 acc[4][4];
  #pragma unroll
  for (int m = 0; m < 4; ++m)
    #pragma unroll
    for (int n = 0; n < 4; ++n) acc[m][n] = f32x4{0.f, 0.f, 0.f, 0.f};

  const u16* Ab = A + (size_t)mb * 128 * K;
  const u16* Bb = Bt + (size_t)nb * 128 * K;
  const int r0 = tid >> 2, inn = (tid & 3) * 8;
  const int l0 = (tid & ~63) * 8, l1 = ((256 + tid) & ~63) * 8;

  const int ks1 = (sb + 1) * kps;
  for (int ks = sb * kps; ks < ks1; ++ks) {
    const int k0 = ks * 32;
    __syncthreads();
    gload16(Ab + (size_t)r0 * K + k0 + inn,        lA + l0);
    gload16(Ab + (size_t)(r0 + 64) * K + k0 + inn, lA + l1);
    gload16(Bb + (size_t)r0 * K + k0 + inn,        lB + l0);
    gload16(Bb + (size_t)(r0 + 64) * K + k0 + inn, lB + l1);
    __syncthreads();
    bf16x8 af[4], bg[4];
    #pragma unroll
    for (int m = 0; m < 4; ++m)
      af[m] = *reinterpret_cast<const bf16x8*>(&lA[(wr + m * 16 + lrow) * 32 + lko]);
    #pragma unroll
    for (int n = 0; n < 4; ++n)
      bg[n] = *reinterpret_cast<const bf16x8*>(&lB[(wc + n * 16 + lrow) * 32 + lko]);
    #pragma unroll
    for (int m = 0; m < 4; ++m)
      #pragma unroll
      for (int n = 0; n < 4; ++n)
        acc[m][n] = __builtin_amdgcn_mfma_f32_16x16x32_bf16(af[m], bg[n], acc[m][n], 0, 0, 0);
  }

  float* C = Cp + (size_t)sb * M * N;
  #pragma unroll
  for (int m = 0; m < 4; ++m) {
    const int rb = mb * 128 + wr + m * 16 + (lane >> 4) * 4;
    #pragma unroll
    for (int n = 0; n < 4; ++n) {
      const int col = nb * 128 + wc + n * 16 + (lane & 15);
      #pragma unroll
      for (int j = 0; j < 4; ++j)
        __builtin_nontemporal_store(acc[m][n][j], &C[(size_t)(rb + j) * N + col]);
    }
  }
}

// ---------------------------------------------------------------------------
// Split-K reduce + bias + relu -> bf16, vectorized
// ---------------------------------------------------------------------------
__global__ __launch_bounds__(256) void reduce_bias_relu_bf16(
    const float* __restrict__ part, int S, size_t MN,
    const float* __restrict__ bias, int nmask, u16* __restrict__ out)
{
  const size_t n8 = MN >> 3;
  for (size_t i8 = blockIdx.x * 256ull + threadIdx.x; i8 < n8; i8 += (size_t)gridDim.x * 256) {
    const size_t base = i8 * 8;
    f32x4 lo = {0.f, 0.f, 0.f, 0.f}, hi = {0.f, 0.f, 0.f, 0.f};
    for (int k = 0; k < S; ++k) {
      const float* p = part + (size_t)k * MN + base;
      f32x4 a = __builtin_nontemporal_load(reinterpret_cast<const f32x4*>(p));
      f32x4 b = __builtin_nontemporal_load(reinterpret_cast<const f32x4*>(p + 4));
      lo += a; hi += b;
    }
    const int bb = (int)(base & (size_t)nmask);
    const f32x4 b0 = *reinterpret_cast<const f32x4*>(bias + bb);
    const f32x4 b1 = *reinterpret_cast<const f32x4*>(bias + bb + 4);
    u16x8 v;
    #pragma unroll
    for (int e = 0; e < 4; ++e) v[e] = f2bf(fmaxf(lo[e] + b0[e], 0.f));
    #pragma unroll
    for (int e = 0; e < 4; ++e) v[4 + e] = f2bf(fmaxf(hi[e] + b1[e], 0.f));
    *reinterpret_cast<u16x8*>(out + base) = v;
  }
}

// ---------------------------------------------------------------------------
// Merged layer-3 reduce + bias + relu + final dot
// ---------------------------------------------------------------------------
__global__ __launch_bounds__(256) void reduce3_final(
    const float* __restrict__ part, const float* __restrict__ bd3,
    const float* __restrict__ Wout, const float* __restrict__ bout,
    float* __restrict__ out)
{
  const int row = blockIdx.x * 4 + (threadIdx.x >> 6);
  const int lane = threadIdx.x & 63;
  const size_t MN = (size_t)BATCH * HD3;
  const size_t base = (size_t)row * HD3;
  float s = 0.f;
  #pragma unroll
  for (int i = 0; i < 4; ++i) {
    const int e = lane + i * 64;
    float v = 0.f;
    #pragma unroll
    for (int k = 0; k < 4; ++k)
      v += __builtin_nontemporal_load(&part[(size_t)k * MN + base + e]);
    v = fmaxf(v + bd3[e], 0.f);
    s += v * Wout[e];
  }
  #pragma unroll
  for (int off = 32; off; off >>= 1) s += __shfl_down(s, off, 64);
  if (lane == 0) out[row] = s + bout[0];
}

// ---------------------------------------------------------------------------
extern "C" void kernel_launch(void* const* d_in, const int* in_sizes, int n_in,
                              void* d_out, int out_size, void* d_ws, size_t ws_size,
                              hipStream_t stream)
{
  const int*   cat    = (const int*)  d_in[0];
  const float* num    = (const float*)d_in[1];
  const float* tables = (const float*)d_in[2];
  const float* nemb   = (const float*)d_in[3];
  const float* Wse1   = (const float*)d_in[4];
  const float* Wse2   = (const float*)d_in[5];
  const float* Wbil   = (const float*)d_in[6];
  const float* Wd1    = (const float*)d_in[7];
  const float* bd1    = (const float*)d_in[8];
  const float* Wd2    = (const float*)d_in[9];
  const float* bd2    = (const float*)d_in[10];
  const float* Wd3    = (const float*)d_in[11];
  const float* bd3    = (const float*)d_in[12];
  const float* Wout   = (const float*)d_in[13];
  const float* bout   = (const float*)d_in[14];

  char* ws = (char*)d_ws;
  u16*   hid  = (u16*)  (ws + 0ull);           // 194,248,704  bf16 [4096][23712]
  u16*   W1t  = (u16*)  (ws + 194248704ull);   //  48,562,176  bf16 [1024][23712]
  float* part = (float*)(ws + 242810880ull);   //  67,108,864  f32 splitK partials
  u16*   W2t  = (u16*)  (ws + 309919744ull);   //   1,048,576
  u16*   W3t  = (u16*)  (ws + 310968320ull);   //     262,144
  u16*   h1b  = (u16*)  (ws + 0ull);           // dead-hid reuse
  u16*   h2b  = (u16*)  (ws + 8388608ull);

  // merged prep: fuse-front blocks [0,2048) + transpose blocks [2048, 2048+24352)
  prep_all<<<BATCH / 2 + 741 * 32 + 512 + 128, 256, 0, stream>>>(
      cat, num, tables, nemb, Wse1, Wse2, Wbil, hid, Wd1, Wd2, Wd3, W1t, W2t, W3t);

  gemm8p_bf16<<<256, 512, 0, stream>>>(hid, W1t, part, BATCH, HD1, KHID, 741, 186);
  reduce_bias_relu_bf16<<<2048, 256, 0, stream>>>(part, 4, (size_t)BATCH * HD1, bd1, HD1 - 1, h1b);

  gemm_bf16<<<dim3(BATCH / 128, HD2 / 128, 2), 256, 0, stream>>>(h1b, W2t, part, BATCH, HD2, HD1, 16);
  reduce_bias_relu_bf16<<<1024, 256, 0, stream>>>(part, 2, (size_t)BATCH * HD2, bd2, HD2 - 1, h2b);

  gemm_bf16<<<dim3(BATCH / 128, HD3 / 128, 4), 256, 0, stream>>>(h2b, W3t, part, BATCH, HD3, HD2, 4);
  reduce3_final<<<BATCH / 4, 256, 0, stream>>>(part, bd3, Wout, bout, (float*)d_out);
}

// Round 13
// 332.699 us; speedup vs baseline: 1.0282x; 1.0226x over previous
//
#include <hip/hip_runtime.h>

typedef unsigned short u16;
typedef __attribute__((ext_vector_type(8))) __bf16 bf16x8;
typedef __attribute__((ext_vector_type(4))) float f32x4;
typedef __attribute__((ext_vector_type(4))) unsigned short u16x4;
typedef __attribute__((ext_vector_type(8))) unsigned short u16x8;

#define NF    39
#define NNUM  13
#define NCAT  26
#define VOC   100000
#define NPAIR 741
#define KHID  23712   /* 2*741*16 */
#define BATCH 4096
#define HD1   1024
#define HD2   512
#define HD3   256

__device__ __forceinline__ u16 f2bf(float f) {
  unsigned u = __builtin_bit_cast(unsigned, f);
  return (u16)((u + 0x7fffu + ((u >> 16) & 1u)) >> 16);   // RNE
}

__device__ __forceinline__ void gload16(const void* g, void* l) {
  __builtin_amdgcn_global_load_lds((const __attribute__((address_space(1))) void*)g,
                                   (__attribute__((address_space(3))) void*)l, 16, 0, 0);
}

// ---------------------------------------------------------------------------
// Front end, 2 rows per block (round-10 proven)
// ---------------------------------------------------------------------------
__global__ __launch_bounds__(256) void fuse_front(
    const int* __restrict__ cat, const float* __restrict__ num,
    const float* __restrict__ tables, const float* __restrict__ nemb,
    const float* __restrict__ Wse1, const float* __restrict__ Wse2,
    const float* __restrict__ Wbil, u16* __restrict__ hid)
{
  __shared__ float xs[2][NF][16];
  __shared__ float wb[NF][16][16];
  __shared__ float pr[2][NF][16];
  __shared__ float Zs[2][NF], Ts[2][NNUM], As[2][NF];
  __shared__ unsigned char pis[NPAIR], pjs[NPAIR];

  const int b0 = blockIdx.x * 2;
  const int tid = threadIdx.x;

  for (int i = tid; i < NF * 64; i += 256)
    ((f32x4*)wb)[i] = ((const f32x4*)Wbil)[i];

  for (int t = tid; t < 2 * NNUM * 16; t += 256) {
    int r = t / (NNUM * 16), t2 = t % (NNUM * 16);
    int f = t2 >> 4, e = t2 & 15;
    xs[r][f][e] = num[(b0 + r) * NNUM + f] * nemb[t2];
  }
  for (int t = tid; t < 2 * NCAT * 16; t += 256) {
    int r = t / (NCAT * 16), t2 = t % (NCAT * 16);
    int c = t2 >> 4, e = t2 & 15;
    int cv = cat[(b0 + r) * NCAT + c];
    xs[r][NNUM + c][e] = tables[((size_t)c * VOC + cv) * 16 + e];
  }
  for (int p = tid; p < NPAIR; p += 256) {
    int i = 0, rs = 0;
    while (p >= rs + (NF - 1 - i)) { rs += NF - 1 - i; ++i; }
    pis[p] = (unsigned char)i;
    pjs[p] = (unsigned char)(i + 1 + (p - rs));
  }
  __syncthreads();

  if (tid < 2 * NF) {
    int r = tid / NF, f = tid % NF;
    float s = 0.f;
    #pragma unroll
    for (int e = 0; e < 16; ++e) s += xs[r][f][e];
    Zs[r][f] = s * (1.f / 16.f);
  }
  __syncthreads();
  if (tid < 2 * NNUM) {
    int r = tid / NNUM, o = tid % NNUM;
    float s = 0.f;
    for (int f = 0; f < NF; ++f) s += Zs[r][f] * Wse1[f * NNUM + o];
    Ts[r][o] = fmaxf(s, 0.f);
  }
  __syncthreads();
  if (tid < 2 * NF) {
    int r = tid / NF, f = tid % NF;
    float s = 0.f;
    for (int q = 0; q < NNUM; ++q) s += Ts[r][q] * Wse2[q * NF + f];
    As[r][f] = fmaxf(s, 0.f);
  }
  for (int t = tid; t < 2 * NF * 16; t += 256) {
    int r = t / (NF * 16), t2 = t % (NF * 16);
    int f = t2 >> 4, d = t2 & 15;
    float s = 0.f;
    #pragma unroll
    for (int e = 0; e < 16; ++e) s += xs[r][f][e] * wb[f][e][d];
    pr[r][f][d] = s;
  }
  __syncthreads();

  for (int idx = tid; idx < 2 * NPAIR * 2; idx += 256) {
    const int r = idx / (NPAIR * 2), idx2 = idx % (NPAIR * 2);
    const int p = idx2 >> 1, e0 = (idx2 & 1) * 8;
    const int i = pis[p], j = pjs[p];
    const float aa = As[r][i] * As[r][j];
    u16* hr = hid + (size_t)(b0 + r) * KHID;
    u16x8 vb, vs;
    #pragma unroll
    for (int e = 0; e < 8; ++e) {
      float bv = pr[r][i][e0 + e] * xs[r][j][e0 + e];
      vb[e] = f2bf(bv);
      vs[e] = f2bf(aa * bv);
    }
    *reinterpret_cast<u16x8*>(hr + NPAIR * 16 + p * 16 + e0) = vb;
    *reinterpret_cast<u16x8*>(hr + p * 16 + e0) = vs;
  }
}

// ---------------------------------------------------------------------------
// Merged transpose+cast (round-9/10 proven)
// ---------------------------------------------------------------------------
__global__ __launch_bounds__(256) void transpose_all(
    const float* __restrict__ Wd1, const float* __restrict__ Wd2,
    const float* __restrict__ Wd3, u16* __restrict__ W1t,
    u16* __restrict__ W2t, u16* __restrict__ W3t)
{
  __shared__ float t[32][33];
  const int bid = blockIdx.x;
  const float* in; u16* out; int K, N, kb, nb;
  if (bid < 741 * 32)        { in = Wd1; out = W1t; K = KHID; N = HD1; kb = bid % 741; nb = bid / 741; }
  else if (bid < 741 * 32 + 512) { int r = bid - 741 * 32; in = Wd2; out = W2t; K = HD1; N = HD2; kb = r % 32; nb = r / 32; }
  else                       { int r = bid - 741 * 32 - 512; in = Wd3; out = W3t; K = HD2; N = HD3; kb = r % 16; nb = r / 16; }

  const int k0 = kb * 32, n0 = nb * 32;
  const int c = threadIdx.x & 31, r = threadIdx.x >> 5;
  #pragma unroll
  for (int it = 0; it < 4; ++it)
    t[r + it * 8][c] = in[(size_t)(k0 + r + it * 8) * N + n0 + c];
  __syncthreads();
  const int n = threadIdx.x >> 3, kq = (threadIdx.x & 7) * 4;
  u16x4 v;
  #pragma unroll
  for (int q = 0; q < 4; ++q) v[q] = f2bf(t[kq + q][n]);
  *reinterpret_cast<u16x4*>(out + (size_t)(n0 + n) * K + k0 + kq) = v;
}

// ---------------------------------------------------------------------------
// 256x256 8-wave m201-style fine-phase GEMM (round-10 benched best).
// Per-tile 4 phases of 16 MFMA; single per-tile vmcnt(6) at P3 end;
// prologue vmcnt(6) forces A0,B0,A1,B1. Slot write-after-read safety is
// barrier-carried. absmax canary 2.980232e-08.
// ---------------------------------------------------------------------------
__global__ __launch_bounds__(512, 2) void gemm8p_bf16(
    const u16* __restrict__ A, const u16* __restrict__ Bt,
    float* __restrict__ Cp, int M, int N, int K, int totku, int kpb)
{
  __shared__ __align__(16) u16 lds[65536];   // A slots @0, B slots @32768

  const int tid = threadIdx.x;
  const int wid = tid >> 6, lane = tid & 63;

  const int d = blockIdx.x;
  const int x = d & 7, jj = d >> 3;
  const int mb = ((x & 3) << 2) | (jj & 3);
  const int nb = (jj >> 2) & 3;
  const int sb = ((x >> 2) << 1) | (jj >> 4);

  const int ks0 = sb * kpb;
  const int kunits = (totku - ks0 < kpb) ? (totku - ks0) : kpb;
  const int ftiles = kunits >> 1;

  const int wm = wid >> 2, wn = wid & 3;
  const int lrow = lane & 15, c0 = lane >> 4;

  const int rr = tid >> 2, cc = tid & 3, csrc = cc ^ ((rr >> 1) & 3);
  const u16* pAg = A  + (size_t)((size_t)mb * 256 + rr) * K + (size_t)ks0 * 32 + csrc * 8;
  const u16* pBg = Bt + (size_t)((size_t)nb * 256 + rr) * K + (size_t)ks0 * 32 + csrc * 8;
  const size_t rsk = (size_t)128 * K;
  const int dstoff = tid * 8;

  int offA[8], offB[4];
  #pragma unroll
  for (int m = 0; m < 8; ++m) {
    int r = wm * 128 + m * 16 + lrow;
    offA[m] = r * 32 + ((c0 ^ ((r >> 1) & 3)) << 3);
  }
  #pragma unroll
  for (int n = 0; n < 4; ++n) {
    int r = wn * 64 + n * 16 + lrow;
    offB[n] = r * 32 + ((c0 ^ ((r >> 1) & 3)) << 3);
  }

#define STAGE_A(g) { int sg = ((g) < kunits) ? (g) : (kunits - 1);          \
    const u16* s_ = pAg + (size_t)sg * 32;                                   \
    u16* dp_ = lds + (((g) & 3) * 8192) + dstoff;                            \
    gload16(s_, dp_); gload16(s_ + rsk, dp_ + 4096); }
#define STAGE_B(g) { int sg = ((g) < kunits) ? (g) : (kunits - 1);          \
    const u16* s_ = pBg + (size_t)sg * 32;                                   \
    u16* dp_ = lds + 32768 + (((g) & 3) * 8192) + dstoff;                    \
    gload16(s_, dp_); gload16(s_ + rsk, dp_ + 4096); }

  f32x4 acc[8][4];
  #pragma unroll
  for (int m = 0; m < 8; ++m)
    #pragma unroll
    for (int n = 0; n < 4; ++n) acc[m][n] = f32x4{0.f, 0.f, 0.f, 0.f};

  STAGE_A(0); STAGE_B(0); STAGE_A(1); STAGE_B(1); STAGE_A(2); STAGE_B(2); STAGE_B(3);
  asm volatile("s_waitcnt vmcnt(6)" ::: "memory");   // forces A0,B0,A1,B1
  __builtin_amdgcn_s_barrier();

  bf16x8 a0, a1, a2, a3, bg0, bg1, bg2, bg3;

  for (int tt = 0; tt < ftiles; ++tt) {
    const int g0 = tt << 1;
    const u16* As0 = lds + ((g0 & 3) * 8192);
    const u16* As1 = lds + (((g0 + 1) & 3) * 8192);
    const u16* Bs0 = lds + 32768 + ((g0 & 3) * 8192);
    const u16* Bs1 = lds + 32768 + (((g0 + 1) & 3) * 8192);

    // ---- P0: af(m0-3,kk0)+bg(kk0); stage A(g0+3)
    a0 = *reinterpret_cast<const bf16x8*>(As0 + offA[0]);
    a1 = *reinterpret_cast<const bf16x8*>(As0 + offA[1]);
    a2 = *reinterpret_cast<const bf16x8*>(As0 + offA[2]);
    a3 = *reinterpret_cast<const bf16x8*>(As0 + offA[3]);
    bg0 = *reinterpret_cast<const bf16x8*>(Bs0 + offB[0]);
    bg1 = *reinterpret_cast<const bf16x8*>(Bs0 + offB[1]);
    bg2 = *reinterpret_cast<const bf16x8*>(Bs0 + offB[2]);
    bg3 = *reinterpret_cast<const bf16x8*>(Bs0 + offB[3]);
    STAGE_A(g0 + 3);
    __builtin_amdgcn_sched_barrier(0);
    __builtin_amdgcn_s_barrier();
    asm volatile("s_waitcnt lgkmcnt(0)" ::: "memory");
    __builtin_amdgcn_sched_barrier(0);
    __builtin_amdgcn_s_setprio(1);
    acc[0][0] = __builtin_amdgcn_mfma_f32_16x16x32_bf16(a0, bg0, acc[0][0], 0, 0, 0);
    acc[0][1] = __builtin_amdgcn_mfma_f32_16x16x32_bf16(a0, bg1, acc[0][1], 0, 0, 0);
    acc[0][2] = __builtin_amdgcn_mfma_f32_16x16x32_bf16(a0, bg2, acc[0][2], 0, 0, 0);
    acc[0][3] = __builtin_amdgcn_mfma_f32_16x16x32_bf16(a0, bg3, acc[0][3], 0, 0, 0);
    acc[1][0] = __builtin_amdgcn_mfma_f32_16x16x32_bf16(a1, bg0, acc[1][0], 0, 0, 0);
    acc[1][1] = __builtin_amdgcn_mfma_f32_16x16x32_bf16(a1, bg1, acc[1][1], 0, 0, 0);
    acc[1][2] = __builtin_amdgcn_mfma_f32_16x16x32_bf16(a1, bg2, acc[1][2], 0, 0, 0);
    acc[1][3] = __builtin_amdgcn_mfma_f32_16x16x32_bf16(a1, bg3, acc[1][3], 0, 0, 0);
    acc[2][0] = __builtin_amdgcn_mfma_f32_16x16x32_bf16(a2, bg0, acc[2][0], 0, 0, 0);
    acc[2][1] = __builtin_amdgcn_mfma_f32_16x16x32_bf16(a2, bg1, acc[2][1], 0, 0, 0);
    acc[2][2] = __builtin_amdgcn_mfma_f32_16x16x32_bf16(a2, bg2, acc[2][2], 0, 0, 0);
    acc[2][3] = __builtin_amdgcn_mfma_f32_16x16x32_bf16(a2, bg3, acc[2][3], 0, 0, 0);
    acc[3][0] = __builtin_amdgcn_mfma_f32_16x16x32_bf16(a3, bg0, acc[3][0], 0, 0, 0);
    acc[3][1] = __builtin_amdgcn_mfma_f32_16x16x32_bf16(a3, bg1, acc[3][1], 0, 0, 0);
    acc[3][2] = __builtin_amdgcn_mfma_f32_16x16x32_bf16(a3, bg2, acc[3][2], 0, 0, 0);
    acc[3][3] = __builtin_amdgcn_mfma_f32_16x16x32_bf16(a3, bg3, acc[3][3], 0, 0, 0);
    __builtin_amdgcn_s_setprio(0);
    __builtin_amdgcn_sched_barrier(0);
    __builtin_amdgcn_s_barrier();

    // ---- P1: af(m4-7,kk0); stage B(g0+4)
    a0 = *reinterpret_cast<const bf16x8*>(As0 + offA[4]);
    a1 = *reinterpret_cast<const bf16x8*>(As0 + offA[5]);
    a2 = *reinterpret_cast<const bf16x8*>(As0 + offA[6]);
    a3 = *reinterpret_cast<const bf16x8*>(As0 + offA[7]);
    STAGE_B(g0 + 4);
    __builtin_amdgcn_sched_barrier(0);
    __builtin_amdgcn_s_barrier();
    asm volatile("s_waitcnt lgkmcnt(0)" ::: "memory");
    __builtin_amdgcn_sched_barrier(0);
    __builtin_amdgcn_s_setprio(1);
    acc[4][0] = __builtin_amdgcn_mfma_f32_16x16x32_bf16(a0, bg0, acc[4][0], 0, 0, 0);
    acc[4][1] = __builtin_amdgcn_mfma_f32_16x16x32_bf16(a0, bg1, acc[4][1], 0, 0, 0);
    acc[4][2] = __builtin_amdgcn_mfma_f32_16x16x32_bf16(a0, bg2, acc[4][2], 0, 0, 0);
    acc[4][3] = __builtin_amdgcn_mfma_f32_16x16x32_bf16(a0, bg3, acc[4][3], 0, 0, 0);
    acc[5][0] = __builtin_amdgcn_mfma_f32_16x16x32_bf16(a1, bg0, acc[5][0], 0, 0, 0);
    acc[5][1] = __builtin_amdgcn_mfma_f32_16x16x32_bf16(a1, bg1, acc[5][1], 0, 0, 0);
    acc[5][2] = __builtin_amdgcn_mfma_f32_16x16x32_bf16(a1, bg2, acc[5][2], 0, 0, 0);
    acc[5][3] = __builtin_amdgcn_mfma_f32_16x16x32_bf16(a1, bg3, acc[5][3], 0, 0, 0);
    acc[6][0] = __builtin_amdgcn_mfma_f32_16x16x32_bf16(a2, bg0, acc[6][0], 0, 0, 0);
    acc[6][1] = __builtin_amdgcn_mfma_f32_16x16x32_bf16(a2, bg1, acc[6][1], 0, 0, 0);
    acc[6][2] = __builtin_amdgcn_mfma_f32_16x16x32_bf16(a2, bg2, acc[6][2], 0, 0, 0);
    acc[6][3] = __builtin_amdgcn_mfma_f32_16x16x32_bf16(a2, bg3, acc[6][3], 0, 0, 0);
    acc[7][0] = __builtin_amdgcn_mfma_f32_16x16x32_bf16(a3, bg0, acc[7][0], 0, 0, 0);
    acc[7][1] = __builtin_amdgcn_mfma_f32_16x16x32_bf16(a3, bg1, acc[7][1], 0, 0, 0);
    acc[7][2] = __builtin_amdgcn_mfma_f32_16x16x32_bf16(a3, bg2, acc[7][2], 0, 0, 0);
    acc[7][3] = __builtin_amdgcn_mfma_f32_16x16x32_bf16(a3, bg3, acc[7][3], 0, 0, 0);
    __builtin_amdgcn_s_setprio(0);
    __builtin_amdgcn_sched_barrier(0);
    __builtin_amdgcn_s_barrier();

    // ---- P2: af(m0-3,kk1)+bg(kk1); stage A(g0+4)
    a0 = *reinterpret_cast<const bf16x8*>(As1 + offA[0]);
    a1 = *reinterpret_cast<const bf16x8*>(As1 + offA[1]);
    a2 = *reinterpret_cast<const bf16x8*>(As1 + offA[2]);
    a3 = *reinterpret_cast<const bf16x8*>(As1 + offA[3]);
    bg0 = *reinterpret_cast<const bf16x8*>(Bs1 + offB[0]);
    bg1 = *reinterpret_cast<const bf16x8*>(Bs1 + offB[1]);
    bg2 = *reinterpret_cast<const bf16x8*>(Bs1 + offB[2]);
    bg3 = *reinterpret_cast<const bf16x8*>(Bs1 + offB[3]);
    STAGE_A(g0 + 4);
    __builtin_amdgcn_sched_barrier(0);
    __builtin_amdgcn_s_barrier();
    asm volatile("s_waitcnt lgkmcnt(0)" ::: "memory");
    __builtin_amdgcn_sched_barrier(0);
    __builtin_amdgcn_s_setprio(1);
    acc[0][0] = __builtin_amdgcn_mfma_f32_16x16x32_bf16(a0, bg0, acc[0][0], 0, 0, 0);
    acc[0][1] = __builtin_amdgcn_mfma_f32_16x16x32_bf16(a0, bg1, acc[0][1], 0, 0, 0);
    acc[0][2] = __builtin_amdgcn_mfma_f32_16x16x32_bf16(a0, bg2, acc[0][2], 0, 0, 0);
    acc[0][3] = __builtin_amdgcn_mfma_f32_16x16x32_bf16(a0, bg3, acc[0][3], 0, 0, 0);
    acc[1][0] = __builtin_amdgcn_mfma_f32_16x16x32_bf16(a1, bg0, acc[1][0], 0, 0, 0);
    acc[1][1] = __builtin_amdgcn_mfma_f32_16x16x32_bf16(a1, bg1, acc[1][1], 0, 0, 0);
    acc[1][2] = __builtin_amdgcn_mfma_f32_16x16x32_bf16(a1, bg2, acc[1][2], 0, 0, 0);
    acc[1][3] = __builtin_amdgcn_mfma_f32_16x16x32_bf16(a1, bg3, acc[1][3], 0, 0, 0);
    acc[2][0] = __builtin_amdgcn_mfma_f32_16x16x32_bf16(a2, bg0, acc[2][0], 0, 0, 0);
    acc[2][1] = __builtin_amdgcn_mfma_f32_16x16x32_bf16(a2, bg1, acc[2][1], 0, 0, 0);
    acc[2][2] = __builtin_amdgcn_mfma_f32_16x16x32_bf16(a2, bg2, acc[2][2], 0, 0, 0);
    acc[2][3] = __builtin_amdgcn_mfma_f32_16x16x32_bf16(a2, bg3, acc[2][3], 0, 0, 0);
    acc[3][0] = __builtin_amdgcn_mfma_f32_16x16x32_bf16(a3, bg0, acc[3][0], 0, 0, 0);
    acc[3][1] = __builtin_amdgcn_mfma_f32_16x16x32_bf16(a3, bg1, acc[3][1], 0, 0, 0);
    acc[3][2] = __builtin_amdgcn_mfma_f32_16x16x32_bf16(a3, bg2, acc[3][2], 0, 0, 0);
    acc[3][3] = __builtin_amdgcn_mfma_f32_16x16x32_bf16(a3, bg3, acc[3][3], 0, 0, 0);
    __builtin_amdgcn_s_setprio(0);
    __builtin_amdgcn_sched_barrier(0);
    __builtin_amdgcn_s_barrier();

    // ---- P3: af(m4-7,kk1); stage B(g0+5); single per-tile vmcnt(6)
    a0 = *reinterpret_cast<const bf16x8*>(As1 + offA[4]);
    a1 = *reinterpret_cast<const bf16x8*>(As1 + offA[5]);
    a2 = *reinterpret_cast<const bf16x8*>(As1 + offA[6]);
    a3 = *reinterpret_cast<const bf16x8*>(As1 + offA[7]);
    STAGE_B(g0 + 5);
    __builtin_amdgcn_sched_barrier(0);
    __builtin_amdgcn_s_barrier();
    asm volatile("s_waitcnt lgkmcnt(0)" ::: "memory");
    __builtin_amdgcn_sched_barrier(0);
    __builtin_amdgcn_s_setprio(1);
    acc[4][0] = __builtin_amdgcn_mfma_f32_16x16x32_bf16(a0, bg0, acc[4][0], 0, 0, 0);
    acc[4][1] = __builtin_amdgcn_mfma_f32_16x16x32_bf16(a0, bg1, acc[4][1], 0, 0, 0);
    acc[4][2] = __builtin_amdgcn_mfma_f32_16x16x32_bf16(a0, bg2, acc[4][2], 0, 0, 0);
    acc[4][3] = __builtin_amdgcn_mfma_f32_16x16x32_bf16(a0, bg3, acc[4][3], 0, 0, 0);
    acc[5][0] = __builtin_amdgcn_mfma_f32_16x16x32_bf16(a1, bg0, acc[5][0], 0, 0, 0);
    acc[5][1] = __builtin_amdgcn_mfma_f32_16x16x32_bf16(a1, bg1, acc[5][1], 0, 0, 0);
    acc[5][2] = __builtin_amdgcn_mfma_f32_16x16x32_bf16(a1, bg2, acc[5][2], 0, 0, 0);
    acc[5][3] = __builtin_amdgcn_mfma_f32_16x16x32_bf16(a1, bg3, acc[5][3], 0, 0, 0);
    acc[6][0] = __builtin_amdgcn_mfma_f32_16x16x32_bf16(a2, bg0, acc[6][0], 0, 0, 0);
    acc[6][1] = __builtin_amdgcn_mfma_f32_16x16x32_bf16(a2, bg1, acc[6][1], 0, 0, 0);
    acc[6][2] = __builtin_amdgcn_mfma_f32_16x16x32_bf16(a2, bg2, acc[6][2], 0, 0, 0);
    acc[6][3] = __builtin_amdgcn_mfma_f32_16x16x32_bf16(a2, bg3, acc[6][3], 0, 0, 0);
    acc[7][0] = __builtin_amdgcn_mfma_f32_16x16x32_bf16(a3, bg0, acc[7][0], 0, 0, 0);
    acc[7][1] = __builtin_amdgcn_mfma_f32_16x16x32_bf16(a3, bg1, acc[7][1], 0, 0, 0);
    acc[7][2] = __builtin_amdgcn_mfma_f32_16x16x32_bf16(a3, bg2, acc[7][2], 0, 0, 0);
    acc[7][3] = __builtin_amdgcn_mfma_f32_16x16x32_bf16(a3, bg3, acc[7][3], 0, 0, 0);
    __builtin_amdgcn_s_setprio(0);
    __builtin_amdgcn_sched_barrier(0);
    asm volatile("s_waitcnt vmcnt(6)" ::: "memory");
    __builtin_amdgcn_s_barrier();
  }

  if (kunits & 1) {
    asm volatile("s_waitcnt vmcnt(0)" ::: "memory");
    __builtin_amdgcn_s_barrier();
    const int g = kunits - 1;
    const u16* As = lds + ((g & 3) * 8192);
    const u16* Bs = lds + 32768 + ((g & 3) * 8192);
    bg0 = *reinterpret_cast<const bf16x8*>(Bs + offB[0]);
    bg1 = *reinterpret_cast<const bf16x8*>(Bs + offB[1]);
    bg2 = *reinterpret_cast<const bf16x8*>(Bs + offB[2]);
    bg3 = *reinterpret_cast<const bf16x8*>(Bs + offB[3]);
    #pragma unroll
    for (int m = 0; m < 8; ++m) {
      bf16x8 am = *reinterpret_cast<const bf16x8*>(As + offA[m]);
      acc[m][0] = __builtin_amdgcn_mfma_f32_16x16x32_bf16(am, bg0, acc[m][0], 0, 0, 0);
      acc[m][1] = __builtin_amdgcn_mfma_f32_16x16x32_bf16(am, bg1, acc[m][1], 0, 0, 0);
      acc[m][2] = __builtin_amdgcn_mfma_f32_16x16x32_bf16(am, bg2, acc[m][2], 0, 0, 0);
      acc[m][3] = __builtin_amdgcn_mfma_f32_16x16x32_bf16(am, bg3, acc[m][3], 0, 0, 0);
    }
  }
#undef STAGE_A
#undef STAGE_B

  float* C = Cp + (size_t)sb * M * N;
  #pragma unroll
  for (int m = 0; m < 8; ++m) {
    const int rb = mb * 256 + wm * 128 + m * 16 + (lane >> 4) * 4;
    #pragma unroll
    for (int n = 0; n < 4; ++n) {
      const int col = nb * 256 + wn * 64 + n * 16 + (lane & 15);
      #pragma unroll
      for (int j2 = 0; j2 < 4; ++j2)
        __builtin_nontemporal_store(acc[m][n][j2], &C[(size_t)(rb + j2) * N + col]);
    }
  }
}

// ---------------------------------------------------------------------------
// 128x128 m97-structure GEMM for the small layers 2/3
// ---------------------------------------------------------------------------
__global__ __launch_bounds__(256) void gemm_bf16(
    const u16* __restrict__ A, const u16* __restrict__ Bt,
    float* __restrict__ Cp, int M, int N, int K, int kps)
{
  __shared__ __align__(16) u16 lA[128 * 32];
  __shared__ __align__(16) u16 lB[128 * 32];
  const int tid = threadIdx.x;
  const int mb = blockIdx.x, nb = blockIdx.y, sb = blockIdx.z;
  const int w = tid >> 6, lane = tid & 63;
  const int wr = (w >> 1) * 64, wc = (w & 1) * 64;
  const int lrow = lane & 15, lko = (lane >> 4) * 8;

  f32x4 acc[4][4];
  #pragma unroll
  for (int m = 0; m < 4; ++m)
    #pragma unroll
    for (int n = 0; n < 4; ++n) acc[m][n] = f32x4{0.f, 0.f, 0.f, 0.f};

  const u16* Ab = A + (size_t)mb * 128 * K;
  const u16* Bb = Bt + (size_t)nb * 128 * K;
  const int r0 = tid >> 2, inn = (tid & 3) * 8;
  const int l0 = (tid & ~63) * 8, l1 = ((256 + tid) & ~63) * 8;

  const int ks1 = (sb + 1) * kps;
  for (int ks = sb * kps; ks < ks1; ++ks) {
    const int k0 = ks * 32;
    __syncthreads();
    gload16(Ab + (size_t)r0 * K + k0 + inn,        lA + l0);
    gload16(Ab + (size_t)(r0 + 64) * K + k0 + inn, lA + l1);
    gload16(Bb + (size_t)r0 * K + k0 + inn,        lB + l0);
    gload16(Bb + (size_t)(r0 + 64) * K + k0 + inn, lB + l1);
    __syncthreads();
    bf16x8 af[4], bg[4];
    #pragma unroll
    for (int m = 0; m < 4; ++m)
      af[m] = *reinterpret_cast<const bf16x8*>(&lA[(wr + m * 16 + lrow) * 32 + lko]);
    #pragma unroll
    for (int n = 0; n < 4; ++n)
      bg[n] = *reinterpret_cast<const bf16x8*>(&lB[(wc + n * 16 + lrow) * 32 + lko]);
    #pragma unroll
    for (int m = 0; m < 4; ++m)
      #pragma unroll
      for (int n = 0; n < 4; ++n)
        acc[m][n] = __builtin_amdgcn_mfma_f32_16x16x32_bf16(af[m], bg[n], acc[m][n], 0, 0, 0);
  }

  float* C = Cp + (size_t)sb * M * N;
  #pragma unroll
  for (int m = 0; m < 4; ++m) {
    const int rb = mb * 128 + wr + m * 16 + (lane >> 4) * 4;
    #pragma unroll
    for (int n = 0; n < 4; ++n) {
      const int col = nb * 128 + wc + n * 16 + (lane & 15);
      #pragma unroll
      for (int j = 0; j < 4; ++j)
        __builtin_nontemporal_store(acc[m][n][j], &C[(size_t)(rb + j) * N + col]);
    }
  }
}

// ---------------------------------------------------------------------------
// Split-K reduce + bias + relu -> bf16, vectorized
// ---------------------------------------------------------------------------
__global__ __launch_bounds__(256) void reduce_bias_relu_bf16(
    const float* __restrict__ part, int S, size_t MN,
    const float* __restrict__ bias, int nmask, u16* __restrict__ out)
{
  const size_t n8 = MN >> 3;
  for (size_t i8 = blockIdx.x * 256ull + threadIdx.x; i8 < n8; i8 += (size_t)gridDim.x * 256) {
    const size_t base = i8 * 8;
    f32x4 lo = {0.f, 0.f, 0.f, 0.f}, hi = {0.f, 0.f, 0.f, 0.f};
    for (int k = 0; k < S; ++k) {
      const float* p = part + (size_t)k * MN + base;
      f32x4 a = __builtin_nontemporal_load(reinterpret_cast<const f32x4*>(p));
      f32x4 b = __builtin_nontemporal_load(reinterpret_cast<const f32x4*>(p + 4));
      lo += a; hi += b;
    }
    const int bb = (int)(base & (size_t)nmask);
    const f32x4 b0 = *reinterpret_cast<const f32x4*>(bias + bb);
    const f32x4 b1 = *reinterpret_cast<const f32x4*>(bias + bb + 4);
    u16x8 v;
    #pragma unroll
    for (int e = 0; e < 4; ++e) v[e] = f2bf(fmaxf(lo[e] + b0[e], 0.f));
    #pragma unroll
    for (int e = 0; e < 4; ++e) v[4 + e] = f2bf(fmaxf(hi[e] + b1[e], 0.f));
    *reinterpret_cast<u16x8*>(out + base) = v;
  }
}

// ---------------------------------------------------------------------------
// Merged layer-3 reduce + bias + relu + final dot
// ---------------------------------------------------------------------------
__global__ __launch_bounds__(256) void reduce3_final(
    const float* __restrict__ part, const float* __restrict__ bd3,
    const float* __restrict__ Wout, const float* __restrict__ bout,
    float* __restrict__ out)
{
  const int row = blockIdx.x * 4 + (threadIdx.x >> 6);
  const int lane = threadIdx.x & 63;
  const size_t MN = (size_t)BATCH * HD3;
  const size_t base = (size_t)row * HD3;
  float s = 0.f;
  #pragma unroll
  for (int i = 0; i < 4; ++i) {
    const int e = lane + i * 64;
    float v = 0.f;
    #pragma unroll
    for (int k = 0; k < 4; ++k)
      v += __builtin_nontemporal_load(&part[(size_t)k * MN + base + e]);
    v = fmaxf(v + bd3[e], 0.f);
    s += v * Wout[e];
  }
  #pragma unroll
  for (int off = 32; off; off >>= 1) s += __shfl_down(s, off, 64);
  if (lane == 0) out[row] = s + bout[0];
}

// ---------------------------------------------------------------------------
extern "C" void kernel_launch(void* const* d_in, const int* in_sizes, int n_in,
                              void* d_out, int out_size, void* d_ws, size_t ws_size,
                              hipStream_t stream)
{
  const int*   cat    = (const int*)  d_in[0];
  const float* num    = (const float*)d_in[1];
  const float* tables = (const float*)d_in[2];
  const float* nemb   = (const float*)d_in[3];
  const float* Wse1   = (const float*)d_in[4];
  const float* Wse2   = (const float*)d_in[5];
  const float* Wbil   = (const float*)d_in[6];
  const float* Wd1    = (const float*)d_in[7];
  const float* bd1    = (const float*)d_in[8];
  const float* Wd2    = (const float*)d_in[9];
  const float* bd2    = (const float*)d_in[10];
  const float* Wd3    = (const float*)d_in[11];
  const float* bd3    = (const float*)d_in[12];
  const float* Wout   = (const float*)d_in[13];
  const float* bout   = (const float*)d_in[14];

  char* ws = (char*)d_ws;
  u16*   hid  = (u16*)  (ws + 0ull);           // 194,248,704  bf16 [4096][23712]
  u16*   W1t  = (u16*)  (ws + 194248704ull);   //  48,562,176  bf16 [1024][23712]
  float* part = (float*)(ws + 242810880ull);   //  67,108,864  f32 splitK partials
  u16*   W2t  = (u16*)  (ws + 309919744ull);   //   1,048,576
  u16*   W3t  = (u16*)  (ws + 310968320ull);   //     262,144
  u16*   h1b  = (u16*)  (ws + 0ull);           // dead-hid reuse
  u16*   h2b  = (u16*)  (ws + 8388608ull);

  // round-10 order: transposes first, hid written last (warm in L3 for gemm)
  transpose_all<<<741 * 32 + 512 + 128, 256, 0, stream>>>(Wd1, Wd2, Wd3, W1t, W2t, W3t);
  fuse_front<<<BATCH / 2, 256, 0, stream>>>(cat, num, tables, nemb, Wse1, Wse2, Wbil, hid);

  gemm8p_bf16<<<256, 512, 0, stream>>>(hid, W1t, part, BATCH, HD1, KHID, 741, 186);
  reduce_bias_relu_bf16<<<2048, 256, 0, stream>>>(part, 4, (size_t)BATCH * HD1, bd1, HD1 - 1, h1b);

  gemm_bf16<<<dim3(BATCH / 128, HD2 / 128, 2), 256, 0, stream>>>(h1b, W2t, part, BATCH, HD2, HD1, 16);
  reduce_bias_relu_bf16<<<1024, 256, 0, stream>>>(part, 2, (size_t)BATCH * HD2, bd2, HD2 - 1, h2b);

  gemm_bf16<<<dim3(BATCH / 128, HD3 / 128, 4), 256, 0, stream>>>(h2b, W3t, part, BATCH, HD3, HD2, 4);
  reduce3_final<<<BATCH / 4, 256, 0, stream>>>(part, bd3, Wout, bout, (float*)d_out);
}